// Round 4
// baseline (3384.857 us; speedup 1.0000x reference)
//
#include <hip/hip_runtime.h>
#include <hip/hip_bf16.h>

// HGT layer: N=50000, E=400000, D=256, T=3, R=6, H=4, DK=64.
// Round 3: hoist rel transforms to MFMA batched GEMM (krel/vrel), gather-dot
// attention, counting-sort by dst to kill tacc atomics, bucketed out-GEMM.
// Round-2 path kept as fallback if ws_size < 451 MB.

#define NN 50000
#define EE 400000
#define TN 3
#define RN 6
#define HN 4

typedef __hip_bfloat16 bf16;
using bf16x8 = __attribute__((ext_vector_type(8))) __bf16;
using f32x4  = __attribute__((ext_vector_type(4))) float;

__device__ __forceinline__ float b2f(bf16 h) { return __bfloat162float(h); }
__device__ __forceinline__ float ld(const void* p, long i, int f) {
    return f ? ((const float*)p)[i] : b2f(((const bf16*)p)[i]);
}
__device__ __forceinline__ float blo(unsigned u) { return __uint_as_float(u << 16); }
__device__ __forceinline__ float bhi(unsigned u) { return __uint_as_float(u & 0xffff0000u); }
__device__ __forceinline__ unsigned short f2us(float f) {   // f32 -> bf16 bits, RNE
    unsigned u = __float_as_uint(f);
    return (unsigned short)((u + 0x7fffu + ((u >> 16) & 1u)) >> 16);
}

// ---------------- input dtype sniffer ----------------
__global__ __launch_bounds__(256) void detect_dtype(const void* __restrict__ x,
                                                    int* __restrict__ flag) {
    __shared__ int cnt_s;
    if (threadIdx.x == 0) cnt_s = 0;
    __syncthreads();
    const unsigned short* p = (const unsigned short*)x;
    int c = 0;
    for (int i = threadIdx.x; i < 8192; i += 256) {
        int expo = (p[i] >> 7) & 0xFF;
        if (expo >= 0x97) ++c;
    }
    atomicAdd(&cnt_s, c);
    __syncthreads();
    if (threadIdx.x == 0) *flag = (cnt_s > 64) ? 1 : 0;
}

__global__ __launch_bounds__(256) void sentinel_fill(bf16* __restrict__ out, int n) {
    int i = blockIdx.x * 256 + threadIdx.x;
    if (i < n) out[i] = __float2bfloat16(1.0f);
}

// ---------------- bucket nodes by type ----------------
__global__ __launch_bounds__(256) void bucket_nodes(const int* __restrict__ node_type,
                                                    int* __restrict__ lists,
                                                    int* __restrict__ cnts) {
    __shared__ int lc[TN], lbase[TN];
    int t = threadIdx.x;
    if (t < TN) lc[t] = 0;
    __syncthreads();
    int n = blockIdx.x * 256 + t;
    int pos = -1, ty = 0;
    if (n < NN) {
        ty = node_type[n];
        pos = atomicAdd(&lc[ty], 1);
    }
    __syncthreads();
    if (t < TN) lbase[t] = atomicAdd(&cnts[t], lc[t]);
    __syncthreads();
    if (n < NN) lists[ty * NN + lbase[ty] + pos] = n;
}

// ---------------- k/q/v typed linear (16 same-type nodes / block) ----------------
__global__ __launch_bounds__(256) void k1_kqv(const void* __restrict__ x,
        const void* __restrict__ Wk, const void* __restrict__ bk,
        const void* __restrict__ Wq, const void* __restrict__ bq,
        const void* __restrict__ Wv, const void* __restrict__ bv,
        const int* __restrict__ lists, const int* __restrict__ cnts,
        const int* __restrict__ flag,
        bf16* __restrict__ kb, bf16* __restrict__ qb, bf16* __restrict__ vb) {
    int f = *flag;
    int tt = blockIdx.x % TN, tile = blockIdx.x / TN;
    int cnt = cnts[tt];
    int start = tile * 16;
    if (start >= cnt) return;
    __shared__ __align__(16) float xs[16][256];
    __shared__ int nl[16];
    int t = threadIdx.x;
    if (t < 16) nl[t] = (start + t < cnt) ? lists[tt * NN + start + t] : -1;
    __syncthreads();
    #pragma unroll
    for (int i = 0; i < 16; ++i) {
        int node = nl[i];
        xs[i][t] = (node >= 0) ? ld(x, (long)node * 256 + t, f) : 0.f;
    }
    __syncthreads();
    float ak[16], aq[16], av[16];
    #pragma unroll
    for (int i = 0; i < 16; ++i) { ak[i] = 0.f; aq[i] = 0.f; av[i] = 0.f; }
    long wb = (long)tt * 65536;
    for (int d = 0; d < 256; d += 2) {
        float k0 = ld(Wk, wb + (d + 0) * 256 + t, f), k1 = ld(Wk, wb + (d + 1) * 256 + t, f);
        float q0 = ld(Wq, wb + (d + 0) * 256 + t, f), q1 = ld(Wq, wb + (d + 1) * 256 + t, f);
        float v0 = ld(Wv, wb + (d + 0) * 256 + t, f), v1 = ld(Wv, wb + (d + 1) * 256 + t, f);
        #pragma unroll
        for (int i = 0; i < 16; ++i) {
            float x0 = xs[i][d], x1 = xs[i][d + 1];
            ak[i] += x0 * k0 + x1 * k1;
            aq[i] += x0 * q0 + x1 * q1;
            av[i] += x0 * v0 + x1 * v1;
        }
    }
    float bkv = ld(bk, tt * 256 + t, f);
    float bqv = ld(bq, tt * 256 + t, f);
    float bvv = ld(bv, tt * 256 + t, f);
    #pragma unroll
    for (int i = 0; i < 16; ++i) {
        int node = nl[i];
        if (node < 0) break;
        kb[node * 256 + t] = __float2bfloat16(ak[i] + bkv);
        qb[node * 256 + t] = __float2bfloat16(aq[i] + bqv);
        vb[node * 256 + t] = __float2bfloat16(av[i] + bvv);
    }
}

// ---------------- transpose rel matrices -> MT[r,h][j][d] bf16 ----------------
__global__ __launch_bounds__(256) void transM(const void* __restrict__ rel_att,
        const void* __restrict__ rel_msg, const int* __restrict__ flag,
        unsigned short* __restrict__ MTa, unsigned short* __restrict__ MTm) {
    int f = *flag;
    int m = blockIdx.x;                // 0..47: 24 for att, 24 for msg
    const void* src = (m < 24) ? rel_att : rel_msg;
    unsigned short* dst = (m < 24) ? MTa : MTm;
    long base = (long)(m % 24) * 4096;
    for (int it = 0; it < 16; ++it) {
        int idx = it * 256 + threadIdx.x;
        int d = idx >> 6, j = idx & 63;
        dst[base + (j << 6) + d] = f2us(ld(src, base + idx, f));
    }
}

// ---------------- krel/vrel batched GEMM via MFMA 16x16x32 bf16 ----------------
// block = (ntile of 16 nodes, relation r); wave w = head h.
// C[j][node] = sum_d MT[j][d] * k[node][h*64+d]; A = MT rows, B = k rows (k-contig).
__global__ __launch_bounds__(256) void relgemm(const bf16* __restrict__ kb,
        const bf16* __restrict__ vb,
        const unsigned short* __restrict__ MTa, const unsigned short* __restrict__ MTm,
        unsigned short* __restrict__ krel, unsigned short* __restrict__ vrel) {
    int r = blockIdx.x % RN, ntile = blockIdx.x / RN;
    int nb = ntile * 16;
    int t = threadIdx.x, h = t >> 6, lane = t & 63, ln = lane & 15, quad = lane >> 4;
    __shared__ unsigned short stK[16][264];
    __shared__ unsigned short stV[16][264];

    const unsigned short* kbu = (const unsigned short*)kb;
    const unsigned short* vbu = (const unsigned short*)vb;
    // B fragments: rows of k/v for node nb+ln, head h, K-blocks of 32
    const unsigned short* bkp = kbu + (size_t)(nb + ln) * 256 + h * 64 + quad * 8;
    const unsigned short* bvp = vbu + (size_t)(nb + ln) * 256 + h * 64 + quad * 8;
    bf16x8 Bk0 = *(const bf16x8*)(bkp);
    bf16x8 Bk1 = *(const bf16x8*)(bkp + 32);
    bf16x8 Bv0 = *(const bf16x8*)(bvp);
    bf16x8 Bv1 = *(const bf16x8*)(bvp + 32);

    long mtbase = (long)(r * HN + h) * 4096;
    #pragma unroll
    for (int jt = 0; jt < 4; ++jt) {
        const unsigned short* ap = MTa + mtbase + (jt * 16 + ln) * 64 + quad * 8;
        const unsigned short* mp = MTm + mtbase + (jt * 16 + ln) * 64 + quad * 8;
        bf16x8 Aa0 = *(const bf16x8*)(ap);
        bf16x8 Aa1 = *(const bf16x8*)(ap + 32);
        bf16x8 Am0 = *(const bf16x8*)(mp);
        bf16x8 Am1 = *(const bf16x8*)(mp + 32);
        f32x4 accK = {0.f, 0.f, 0.f, 0.f};
        f32x4 accV = {0.f, 0.f, 0.f, 0.f};
        accK = __builtin_amdgcn_mfma_f32_16x16x32_bf16(Aa0, Bk0, accK, 0, 0, 0);
        accK = __builtin_amdgcn_mfma_f32_16x16x32_bf16(Aa1, Bk1, accK, 0, 0, 0);
        accV = __builtin_amdgcn_mfma_f32_16x16x32_bf16(Am0, Bv0, accV, 0, 0, 0);
        accV = __builtin_amdgcn_mfma_f32_16x16x32_bf16(Am1, Bv1, accV, 0, 0, 0);
        // C: col = ln (node), row = quad*4 + reg (j within tile)
        int jc = h * 64 + jt * 16 + quad * 4;
        ushort4 pk, pv;
        pk.x = f2us(accK[0]); pk.y = f2us(accK[1]); pk.z = f2us(accK[2]); pk.w = f2us(accK[3]);
        pv.x = f2us(accV[0]); pv.y = f2us(accV[1]); pv.z = f2us(accV[2]); pv.w = f2us(accV[3]);
        *(ushort4*)&stK[ln][jc] = pk;
        *(ushort4*)&stV[ln][jc] = pv;
    }
    __syncthreads();
    // coalesced write-out: 512 B per node row
    size_t obase = ((size_t)r * NN + nb) * 256;
    #pragma unroll 4
    for (int i = 0; i < 16; ++i) {
        krel[obase + (size_t)i * 256 + t] = stK[i][t];
        vrel[obase + (size_t)i * 256 + t] = stV[i][t];
    }
}

// ---------------- attention: thread per (edge, head) gather-dot ----------------
__global__ __launch_bounds__(256) void k2p(const bf16* __restrict__ qb,
        const unsigned short* __restrict__ krel, const void* __restrict__ rel_pri,
        const int* __restrict__ esrc, const int* __restrict__ edst,
        const int* __restrict__ etype, const int* __restrict__ flag,
        float* __restrict__ attex, float* __restrict__ denom,
        unsigned* __restrict__ cnt) {
    int f = *flag;
    int i = blockIdx.x * 256 + threadIdx.x;      // i < E*4 exactly
    int e = i >> 2, h = i & 3;
    int r = etype[e], s = esrc[e], dv = edst[e];
    const uint4* qp = (const uint4*)((const unsigned short*)qb + (size_t)dv * 256 + h * 64);
    const uint4* kp = (const uint4*)(krel + (size_t)(r * NN + s) * 256 + h * 64);
    float dot = 0.f;
    #pragma unroll
    for (int ii = 0; ii < 8; ++ii) {
        uint4 a = qp[ii], b = kp[ii];
        dot += blo(a.x) * blo(b.x) + bhi(a.x) * bhi(b.x);
        dot += blo(a.y) * blo(b.y) + bhi(a.y) * bhi(b.y);
        dot += blo(a.z) * blo(b.z) + bhi(a.z) * bhi(b.z);
        dot += blo(a.w) * blo(b.w) + bhi(a.w) * bhi(b.w);
    }
    float attv = dot * ld(rel_pri, r * HN + h, f) * 0.125f;
    attv = fminf(fmaxf(attv, -50.f), 50.f);
    float ex = expf(attv);
    attex[i] = ex;
    atomicAdd(&denom[(dv * RN + r) * HN + h], ex);
    if (h == 0) atomicAdd(&cnt[dv * RN + r], 1u);
}

// ---------------- exclusive scan of per-dst edge counts (1 block) ----------------
__global__ __launch_bounds__(256) void scan_base(const unsigned* __restrict__ cnt,
                                                 int* __restrict__ base) {
    __shared__ int s[256];
    __shared__ int carry_s;
    int t = threadIdx.x;
    if (t == 0) carry_s = 0;
    __syncthreads();
    const int CH = (NN + 1023) / 1024;           // 49 chunks of 1024 nodes
    for (int c = 0; c < CH; ++c) {
        int n0 = c * 1024 + t * 4;
        int vs[4]; int v = 0;
        #pragma unroll
        for (int jj = 0; jj < 4; ++jj) {
            int n = n0 + jj; int x = 0;
            if (n < NN) {
                #pragma unroll
                for (int r = 0; r < RN; ++r) x += (int)cnt[n * RN + r];
            }
            vs[jj] = x; v += x;
        }
        s[t] = v;
        __syncthreads();
        for (int st = 1; st < 256; st <<= 1) {
            int add = (t >= st) ? s[t - st] : 0;
            __syncthreads();
            s[t] += add;
            __syncthreads();
        }
        int run = carry_s + s[t] - v;            // exclusive prefix for n0
        #pragma unroll
        for (int jj = 0; jj < 4; ++jj) {
            int n = n0 + jj;
            if (n < NN) base[n] = run;
            run += vs[jj];
        }
        int total = s[255];
        __syncthreads();
        if (t == 0) carry_s += total;
        __syncthreads();
    }
    if (t == 0) base[NN] = carry_s;
}

// ---------------- scatter edge ids into dst-sorted order ----------------
__global__ __launch_bounds__(256) void scatter_edges(const int* __restrict__ edst,
        const int* __restrict__ base, int* __restrict__ cursor,
        int* __restrict__ sorted) {
    int e = blockIdx.x * 256 + threadIdx.x;
    if (e >= EE) return;
    int dv = edst[e];
    int pos = atomicAdd(&cursor[dv], 1);
    sorted[base[dv] + pos] = e;
}

// ---------------- message aggregation: block per dst, no atomics ----------------
__global__ __launch_bounds__(256) void k4p(const unsigned short* __restrict__ vrel,
        const float* __restrict__ attex, const float* __restrict__ denom,
        const int* __restrict__ sorted, const int* __restrict__ base,
        const int* __restrict__ esrc, const int* __restrict__ etype,
        float* __restrict__ tacc) {
    int n = blockIdx.x, t = threadIdx.x, h = t >> 6;
    int b0 = base[n], b1 = base[n + 1];
    float acc = 0.f;
    for (int idx = b0; idx < b1; ++idx) {
        int e = sorted[idx];
        int r = etype[e], s = esrc[e];
        float w = attex[e * 4 + h] / denom[(n * RN + r) * HN + h];
        float v = __uint_as_float((unsigned)vrel[(size_t)(r * NN + s) * 256 + t] << 16);
        acc += w * v;
    }
    tacc[(size_t)n * 256 + t] = acc;
}

// ---------------- out-linear (bucketed 16 same-type nodes / block) ----------------
__global__ __launch_bounds__(256) void k5a_trans(const float* __restrict__ tacc,
        const unsigned* __restrict__ cnt,
        const void* __restrict__ Wa, const void* __restrict__ ba,
        const int* __restrict__ lists, const int* __restrict__ cnts,
        const int* __restrict__ flag, bf16* __restrict__ trans) {
    int f = *flag;
    int tt = blockIdx.x % TN, tile = blockIdx.x / TN;
    int cntt = cnts[tt];
    int start = tile * 16;
    if (start >= cntt) return;
    __shared__ __align__(16) float xs[16][256];
    __shared__ int nl[16];
    __shared__ float invs[16];
    int t = threadIdx.x;
    if (t < 16) {
        int node = (start + t < cntt) ? lists[tt * NN + start + t] : -1;
        nl[t] = node;
        float iv = 1.f;
        if (node >= 0) {
            int nrel = 0;
            #pragma unroll
            for (int r = 0; r < RN; ++r) nrel += (cnt[node * RN + r] > 0u) ? 1 : 0;
            iv = (nrel > 0) ? 1.f / (float)nrel : 1.f;
        }
        invs[t] = iv;
    }
    __syncthreads();
    #pragma unroll
    for (int i = 0; i < 16; ++i) {
        int node = nl[i];
        xs[i][t] = (node >= 0) ? tacc[(size_t)node * 256 + t] * invs[i] : 0.f;
    }
    __syncthreads();
    float acc[16];
    #pragma unroll
    for (int i = 0; i < 16; ++i) acc[i] = 0.f;
    long wb = (long)tt * 65536;
    for (int d = 0; d < 256; d += 2) {
        float w0 = ld(Wa, wb + (d + 0) * 256 + t, f);
        float w1 = ld(Wa, wb + (d + 1) * 256 + t, f);
        #pragma unroll
        for (int i = 0; i < 16; ++i)
            acc[i] += xs[i][d] * w0 + xs[i][d + 1] * w1;
    }
    float bav = ld(ba, tt * 256 + t, f);
    #pragma unroll
    for (int i = 0; i < 16; ++i) {
        int node = nl[i];
        if (node < 0) break;
        trans[(size_t)node * 256 + t] = __float2bfloat16(acc[i] + bav);
    }
}

// ---------------- skip-gate + LayerNorm + passthrough ----------------
__global__ __launch_bounds__(256) void k5b_ln(const void* __restrict__ x,
        const bf16* __restrict__ trans, const void* __restrict__ skip,
        const void* __restrict__ ln_g, const void* __restrict__ ln_b,
        const int* __restrict__ node_type, const unsigned* __restrict__ cnt,
        const int* __restrict__ flag, void* __restrict__ out) {
    int f = *flag;
    int n = blockIdx.x, t = threadIdx.x;
    int tt = node_type[n];
    int nrel = 0;
    #pragma unroll
    for (int r = 0; r < RN; ++r) nrel += (cnt[n * RN + r] > 0u) ? 1 : 0;
    bool has = (nrel > 0);
    float sk = ld(skip, tt, f);
    float alpha = 1.f / (1.f + expf(-sk));
    float xv = ld(x, (long)n * 256 + t, f);
    float outv = b2f(trans[(size_t)n * 256 + t]) * alpha + xv * (1.f - alpha);
    __shared__ float r1[256], r2[256];
    r1[t] = outv;
    r2[t] = outv * outv;
    __syncthreads();
    for (int st = 128; st > 0; st >>= 1) {
        if (t < st) { r1[t] += r1[t + st]; r2[t] += r2[t + st]; }
        __syncthreads();
    }
    float mu = r1[0] * (1.f / 256.f);
    float ms = r2[0] * (1.f / 256.f);
    float var = fmaxf(ms - mu * mu, 0.f);
    float normed = (outv - mu) * rsqrtf(var + 1e-5f) * ld(ln_g, tt * 256 + t, f)
                 + ld(ln_b, tt * 256 + t, f);
    float resv = has ? normed : xv;
    if (f) ((float*)out)[(long)n * 256 + t] = resv;
    else   ((bf16*)out)[(long)n * 256 + t] = __float2bfloat16(resv);
}

// ================= round-2 fallback kernels (ws too small) =================
__global__ __launch_bounds__(256) void k2_att_soft(const bf16* __restrict__ kb,
        const bf16* __restrict__ qb,
        const void* __restrict__ rel_att, const void* __restrict__ rel_pri,
        const int* __restrict__ esrc, const int* __restrict__ edst,
        const int* __restrict__ etype, const int* __restrict__ flag,
        float* __restrict__ attex, float* __restrict__ denom,
        unsigned* __restrict__ cnt) {
    int f = *flag;
    int e = blockIdx.x;
    int r = etype[e], s = esrc[e], dv = edst[e];
    int t = threadIdx.x, h = t >> 6, dd = t & 63;
    __shared__ float ks[256], qs[256], sred[256];
    ks[t] = b2f(kb[s * 256 + t]);
    qs[t] = b2f(qb[dv * 256 + t]);
    __syncthreads();
    long mb = (long)(r * HN + h) * 4096;
    float acc = 0.f;
    #pragma unroll 8
    for (int d = 0; d < 64; ++d)
        acc += ks[h * 64 + d] * ld(rel_att, mb + d * 64 + dd, f);
    sred[t] = acc * qs[t];
    __syncthreads();
    for (int st = 32; st > 0; st >>= 1) {
        if (dd < st) sred[t] += sred[t + st];
        __syncthreads();
    }
    if (dd == 0) {
        float attv = sred[t] * ld(rel_pri, r * HN + h, f) * 0.125f;
        attv = fminf(fmaxf(attv, -50.f), 50.f);
        float ex = expf(attv);
        attex[e * HN + h] = ex;
        atomicAdd(&denom[(dv * RN + r) * HN + h], ex);
    }
    if (t == 0) atomicAdd(&cnt[dv * RN + r], 1u);
}

__global__ __launch_bounds__(256) void k4_acc(const bf16* __restrict__ vb,
        const void* __restrict__ rel_msg,
        const float* __restrict__ attex, const float* __restrict__ denom,
        const int* __restrict__ esrc, const int* __restrict__ edst,
        const int* __restrict__ etype, const int* __restrict__ flag,
        float* __restrict__ tacc) {
    int f = *flag;
    int e = blockIdx.x;
    int r = etype[e], s = esrc[e], dv = edst[e];
    int t = threadIdx.x, h = t >> 6, dd = t & 63;
    __shared__ float vs[256];
    vs[t] = b2f(vb[s * 256 + t]);
    __syncthreads();
    long mb = (long)(r * HN + h) * 4096;
    float acc = 0.f;
    #pragma unroll 8
    for (int d = 0; d < 64; ++d)
        acc += vs[h * 64 + d] * ld(rel_msg, mb + d * 64 + dd, f);
    float dn = denom[(dv * RN + r) * HN + h];
    float w = (dn > 0.f) ? (attex[e * HN + h] / dn) : 0.f;
    atomicAdd(&tacc[dv * 256 + t], w * acc);
}

__global__ __launch_bounds__(256) void k5_final(const void* __restrict__ x,
        const void* __restrict__ Wa, const void* __restrict__ ba,
        const void* __restrict__ skip, const void* __restrict__ ln_g,
        const void* __restrict__ ln_b, const int* __restrict__ node_type,
        const float* __restrict__ tacc, const unsigned* __restrict__ cnt,
        const int* __restrict__ flag, void* __restrict__ out) {
    int f = *flag;
    int n = blockIdx.x, t = threadIdx.x;
    int tt = node_type[n];
    int nrel = 0;
    #pragma unroll
    for (int r = 0; r < RN; ++r) nrel += (cnt[n * RN + r] > 0u) ? 1 : 0;
    bool has = (nrel > 0);
    float inv = 1.f / (float)(nrel > 0 ? nrel : 1);
    __shared__ __align__(16) float tl[256];
    __shared__ float r1[256], r2[256];
    tl[t] = tacc[n * 256 + t] * inv;
    __syncthreads();
    long wb = (long)tt * 65536;
    float acc = ld(ba, tt * 256 + t, f);
    for (int d = 0; d < 256; d += 2) {
        acc += tl[d] * ld(Wa, wb + (d + 0) * 256 + t, f)
             + tl[d + 1] * ld(Wa, wb + (d + 1) * 256 + t, f);
    }
    float sk = ld(skip, tt, f);
    float alpha = 1.f / (1.f + expf(-sk));
    float xv = ld(x, (long)n * 256 + t, f);
    float outv = acc * alpha + xv * (1.f - alpha);
    r1[t] = outv;
    r2[t] = outv * outv;
    __syncthreads();
    for (int st = 128; st > 0; st >>= 1) {
        if (t < st) { r1[t] += r1[t + st]; r2[t] += r2[t + st]; }
        __syncthreads();
    }
    float mu = r1[0] * (1.f / 256.f);
    float ms = r2[0] * (1.f / 256.f);
    float var = fmaxf(ms - mu * mu, 0.f);
    float normed = (outv - mu) * rsqrtf(var + 1e-5f) * ld(ln_g, tt * 256 + t, f)
                 + ld(ln_b, tt * 256 + t, f);
    float resv = has ? normed : xv;
    if (f) ((float*)out)[(long)n * 256 + t] = resv;
    else   ((bf16*)out)[(long)n * 256 + t] = __float2bfloat16(resv);
}

extern "C" void kernel_launch(void* const* d_in, const int* in_sizes, int n_in,
                              void* d_out, int out_size, void* d_ws, size_t ws_size,
                              hipStream_t stream) {
    const void* x       = d_in[0];
    const void* Wk      = d_in[1];
    const void* bk      = d_in[2];
    const void* Wq      = d_in[3];
    const void* bq      = d_in[4];
    const void* Wv      = d_in[5];
    const void* bv      = d_in[6];
    const void* Wa      = d_in[7];
    const void* ba      = d_in[8];
    const void* rel_pri = d_in[9];
    const void* rel_att = d_in[10];
    const void* rel_msg = d_in[11];
    const void* skip    = d_in[12];
    const void* ln_g    = d_in[13];
    const void* ln_b    = d_in[14];
    const int* node_type = (const int*)d_in[15];
    const int* edge_src  = (const int*)d_in[16];
    const int* edge_dst  = (const int*)d_in[17];
    const int* edge_type = (const int*)d_in[18];
    char* w = (char*)d_ws;

    const size_t NEEDED_FAST = 450986624;
    const size_t NEEDED_FB   = 141000128;

    if (ws_size >= NEEDED_FAST) {
        // ---- fast path layout ----
        bf16*     kb     = (bf16*)(w);                          // 25,600,000
        bf16*     qb     = (bf16*)(w + 25600000);               // 25,600,000 (reused as trans)
        bf16*     vb     = (bf16*)(w + 51200000);               // 25,600,000
        unsigned short* krel = (unsigned short*)(w + 76800000); // 153,600,000
        unsigned short* vrel = (unsigned short*)(w + 230400000);// 153,600,000
        float*    attex  = (float*)(w + 384000000);             // 6,400,000
        float*    tacc   = (float*)(w + 390400000);             // 51,200,000
        unsigned short* MTa = (unsigned short*)(w + 441600000); // 393,216
        unsigned short* MTm = (unsigned short*)(w + 441993216); // 393,216
        int*      nlists = (int*)(w + 442386432);               // 600,000
        int*      base   = (int*)(w + 442986432);               // 200,064
        int*      sorted = (int*)(w + 443186496);               // 1,600,000
        float*    denom  = (float*)(w + 444786496);             // 4,800,000 (zeroed)
        unsigned* cnt    = (unsigned*)(w + 449586496);          // 1,200,000 (zeroed)
        int*      cursor = (int*)(w + 450786496);               // 200,000   (zeroed)
        int*      ncnts  = (int*)(w + 450986496);               // 64        (zeroed)
        int*      flag   = (int*)(w + 450986560);               // 64        (zeroed)

        hipMemsetAsync(w + 444786496, 0, NEEDED_FAST - 444786496, stream);

        detect_dtype<<<dim3(1), dim3(256), 0, stream>>>(x, flag);
        bucket_nodes<<<dim3((NN + 255) / 256), dim3(256), 0, stream>>>(node_type, nlists, ncnts);
        transM<<<dim3(48), dim3(256), 0, stream>>>(rel_att, rel_msg, flag, MTa, MTm);
        k1_kqv<<<dim3(TN * ((NN + 15) / 16)), dim3(256), 0, stream>>>(
            x, Wk, bk, Wq, bq, Wv, bv, nlists, ncnts, flag, kb, qb, vb);
        relgemm<<<dim3((NN / 16) * RN), dim3(256), 0, stream>>>(
            kb, vb, MTa, MTm, krel, vrel);
        k2p<<<dim3(EE * HN / 256), dim3(256), 0, stream>>>(
            qb, krel, rel_pri, edge_src, edge_dst, edge_type, flag, attex, denom, cnt);
        scan_base<<<dim3(1), dim3(256), 0, stream>>>(cnt, base);
        scatter_edges<<<dim3((EE + 255) / 256), dim3(256), 0, stream>>>(
            edge_dst, base, cursor, sorted);
        k4p<<<dim3(NN), dim3(256), 0, stream>>>(
            vrel, attex, denom, sorted, base, edge_src, edge_type, tacc);
        k5a_trans<<<dim3(TN * ((NN + 15) / 16)), dim3(256), 0, stream>>>(
            tacc, cnt, Wa, ba, nlists, ncnts, flag, qb /*trans*/);
        k5b_ln<<<dim3(NN), dim3(256), 0, stream>>>(
            x, qb /*trans*/, skip, ln_g, ln_b, node_type, cnt, flag, d_out);
        return;
    }

    if (ws_size < NEEDED_FB) {
        sentinel_fill<<<dim3((out_size + 255) / 256), dim3(256), 0, stream>>>(
            (bf16*)d_out, out_size);
        return;
    }

    // ---- round-2 fallback path ----
    bf16*     kb    = (bf16*)(w);
    bf16*     qb    = (bf16*)(w + 25600000);
    bf16*     vb    = (bf16*)(w + 51200000);
    float*    attex = (float*)(w + 76800000);
    int*      nlists= (int*)(w + 83200000);
    float*    denom = (float*)(w + 83800000);
    unsigned* cnt   = (unsigned*)(w + 88600000);
    float*    tacc  = (float*)(w + 89800000);
    int*      ncnts = (int*)(w + 141000000);
    int*      flag  = (int*)(w + 141000064);

    hipMemsetAsync(w + 83800000, 0, NEEDED_FB - 83800000, stream);
    detect_dtype<<<dim3(1), dim3(256), 0, stream>>>(x, flag);
    bucket_nodes<<<dim3((NN + 255) / 256), dim3(256), 0, stream>>>(node_type, nlists, ncnts);
    k1_kqv<<<dim3(TN * ((NN + 15) / 16)), dim3(256), 0, stream>>>(
        x, Wk, bk, Wq, bq, Wv, bv, nlists, ncnts, flag, kb, qb, vb);
    k2_att_soft<<<dim3(EE), dim3(256), 0, stream>>>(
        kb, qb, rel_att, rel_pri, edge_src, edge_dst, edge_type, flag, attex, denom, cnt);
    k4_acc<<<dim3(EE), dim3(256), 0, stream>>>(
        vb, rel_msg, attex, denom, edge_src, edge_dst, edge_type, flag, tacc);
    k5_final<<<dim3(NN), dim3(256), 0, stream>>>(
        x, Wa, ba, skip, ln_g, ln_b, node_type, tacc, cnt, flag, d_out);
}

// Round 5
// 1350.561 us; speedup vs baseline: 2.5063x; 2.5063x over previous
//
#include <hip/hip_runtime.h>
#include <hip/hip_bf16.h>

// HGT layer: N=50000, E=400000, D=256, T=3, R=6, H=4, DK=64.
// Round 4: relation-chunked qrel/vrel MFMA GEMM (fits proven 141MB ws),
// seg-sorted edges (seg = r*N+dst) -> atomic-free aggregation, tacc in d_out.

#define NN 50000
#define EE 400000
#define TN 3
#define RN 6
#define HN 4
#define SS (NN * RN)
#define NCHUNK 293   // ceil(SS/1024)

typedef __hip_bfloat16 bf16;
typedef unsigned short u16;
using bf16x8 = __attribute__((ext_vector_type(8))) __bf16;
using f32x4  = __attribute__((ext_vector_type(4))) float;

__device__ __forceinline__ float b2f(bf16 h) { return __bfloat162float(h); }
__device__ __forceinline__ float busf(u16 u) { return __uint_as_float((unsigned)u << 16); }
__device__ __forceinline__ float blo(unsigned u) { return __uint_as_float(u << 16); }
__device__ __forceinline__ float bhi(unsigned u) { return __uint_as_float(u & 0xffff0000u); }
__device__ __forceinline__ u16 f2us(float f) {   // f32 -> bf16 bits, RNE
    unsigned u = __float_as_uint(f);
    return (u16)((u + 0x7fffu + ((u >> 16) & 1u)) >> 16);
}
__device__ __forceinline__ float ld(const void* p, long i, int f) {
    return f ? ((const float*)p)[i] : b2f(((const bf16*)p)[i]);
}

// ---------------- input dtype sniffer (f32 vs bf16 buffers) ----------------
__global__ __launch_bounds__(256) void detect_dtype(const void* __restrict__ x,
                                                    int* __restrict__ flag) {
    __shared__ int cnt_s;
    if (threadIdx.x == 0) cnt_s = 0;
    __syncthreads();
    const u16* p = (const u16*)x;
    int c = 0;
    for (int i = threadIdx.x; i < 8192; i += 256) {
        int expo = (p[i] >> 7) & 0xFF;
        if (expo >= 0x97) ++c;
    }
    atomicAdd(&cnt_s, c);
    __syncthreads();
    if (threadIdx.x == 0) *flag = (cnt_s > 64) ? 1 : 0;
}

// ---------------- bucket nodes by type ----------------
__global__ __launch_bounds__(256) void bucket_nodes(const int* __restrict__ node_type,
                                                    int* __restrict__ lists,
                                                    int* __restrict__ cnts) {
    __shared__ int lc[TN], lbase[TN];
    int t = threadIdx.x;
    if (t < TN) lc[t] = 0;
    __syncthreads();
    int n = blockIdx.x * 256 + t;
    int pos = -1, ty = 0;
    if (n < NN) {
        ty = node_type[n];
        pos = atomicAdd(&lc[ty], 1);
    }
    __syncthreads();
    if (t < TN) lbase[t] = atomicAdd(&cnts[t], lc[t]);
    __syncthreads();
    if (n < NN) lists[ty * NN + lbase[ty] + pos] = n;
}

// ---------------- per-(r,dst) segment edge counts ----------------
__global__ __launch_bounds__(256) void count_seg(const int* __restrict__ edst,
        const int* __restrict__ etype, unsigned* __restrict__ cnt) {
    int e = blockIdx.x * 256 + threadIdx.x;
    if (e >= EE) return;
    atomicAdd(&cnt[etype[e] * NN + edst[e]], 1u);
}

// ---------------- 3-phase exclusive scan over SS segments ----------------
__global__ __launch_bounds__(256) void scanA(const unsigned* __restrict__ cnt,
                                             unsigned* __restrict__ csums) {
    __shared__ unsigned s[256];
    int b = blockIdx.x, t = threadIdx.x;
    int s0 = b * 1024 + t * 4;
    unsigned v = 0;
    if (s0 + 3 < SS) { uint4 u = *(const uint4*)&cnt[s0]; v = u.x + u.y + u.z + u.w; }
    else { for (int j = 0; j < 4; ++j) if (s0 + j < SS) v += cnt[s0 + j]; }
    s[t] = v;
    __syncthreads();
    for (int st = 128; st > 0; st >>= 1) {
        if (t < st) s[t] += s[t + st];
        __syncthreads();
    }
    if (t == 0) csums[b] = s[0];
}

__global__ __launch_bounds__(256) void scanB(unsigned* __restrict__ csums,
                                             int* __restrict__ base) {
    __shared__ unsigned s[512];
    int t = threadIdx.x;
    unsigned a = (t < NCHUNK) ? csums[t] : 0u;
    unsigned b = (256 + t < NCHUNK) ? csums[256 + t] : 0u;
    s[t] = a; s[256 + t] = b;
    __syncthreads();
    for (int st = 1; st < 512; st <<= 1) {
        unsigned x0 = (t >= st) ? s[t - st] : 0u;
        unsigned x1 = (256 + t >= st) ? s[256 + t - st] : 0u;
        __syncthreads();
        s[t] += x0; s[256 + t] += x1;
        __syncthreads();
    }
    if (t < NCHUNK) csums[t] = s[t] - a;
    if (256 + t < NCHUNK) csums[256 + t] = s[256 + t] - b;
    if (t == 0) base[SS] = (int)s[NCHUNK - 1];
}

__global__ __launch_bounds__(256) void scanC(const unsigned* __restrict__ cnt,
        const unsigned* __restrict__ csums, int* __restrict__ base) {
    __shared__ unsigned s[256];
    int b = blockIdx.x, t = threadIdx.x;
    int s0 = b * 1024 + t * 4;
    unsigned vs[4] = {0u, 0u, 0u, 0u};
    if (s0 + 3 < SS) { uint4 u = *(const uint4*)&cnt[s0]; vs[0]=u.x; vs[1]=u.y; vs[2]=u.z; vs[3]=u.w; }
    else { for (int j = 0; j < 4; ++j) if (s0 + j < SS) vs[j] = cnt[s0 + j]; }
    unsigned v = vs[0] + vs[1] + vs[2] + vs[3];
    s[t] = v;
    __syncthreads();
    for (int st = 1; st < 256; st <<= 1) {
        unsigned x = (t >= st) ? s[t - st] : 0u;
        __syncthreads();
        s[t] += x;
        __syncthreads();
    }
    unsigned run = csums[b] + s[t] - v;
    for (int j = 0; j < 4; ++j) {
        if (s0 + j < SS) { base[s0 + j] = (int)run; run += vs[j]; }
    }
}

// ---------------- scatter edges into seg-sorted order (destroys cnt) ----------------
__global__ __launch_bounds__(256) void scatter_edges(const int* __restrict__ edst,
        const int* __restrict__ etype, const int* __restrict__ base,
        unsigned* __restrict__ cnt, int* __restrict__ sorted) {
    int e = blockIdx.x * 256 + threadIdx.x;
    if (e >= EE) return;
    int seg = etype[e] * NN + edst[e];
    unsigned old = atomicSub(&cnt[seg], 1u);
    sorted[base[seg] + (int)old - 1] = e;
}

// ---------------- normalize rel_att -> bf16 (MTa), transpose rel_msg -> bf16 (MTm) ----------------
__global__ __launch_bounds__(256) void transM(const void* __restrict__ rel_att,
        const void* __restrict__ rel_msg, const int* __restrict__ flag,
        u16* __restrict__ MTa, u16* __restrict__ MTm) {
    int f = *flag;
    int m = blockIdx.x;                 // 0..23 att copy, 24..47 msg transpose
    long base = (long)(m % 24) * 4096;
    if (m < 24) {
        for (int it = 0; it < 16; ++it) {
            int idx = it * 256 + threadIdx.x;
            MTa[base + idx] = f2us(ld(rel_att, base + idx, f));
        }
    } else {
        for (int it = 0; it < 16; ++it) {
            int idx = it * 256 + threadIdx.x;
            int d = idx >> 6, j = idx & 63;
            MTm[base + (j << 6) + d] = f2us(ld(rel_msg, base + idx, f));
        }
    }
}

// ---------------- k/q/v typed linear (16 same-type nodes / block) ----------------
__global__ __launch_bounds__(256) void k1_kqv(const void* __restrict__ x,
        const void* __restrict__ Wk, const void* __restrict__ bk,
        const void* __restrict__ Wq, const void* __restrict__ bq,
        const void* __restrict__ Wv, const void* __restrict__ bv,
        const int* __restrict__ lists, const int* __restrict__ cnts,
        const int* __restrict__ flag,
        u16* __restrict__ kb, u16* __restrict__ qb, u16* __restrict__ vb) {
    int f = *flag;
    int tt = blockIdx.x % TN, tile = blockIdx.x / TN;
    int cnt = cnts[tt];
    int start = tile * 16;
    if (start >= cnt) return;
    __shared__ __align__(16) float xs[16][256];
    __shared__ int nl[16];
    int t = threadIdx.x;
    if (t < 16) nl[t] = (start + t < cnt) ? lists[tt * NN + start + t] : -1;
    __syncthreads();
    #pragma unroll
    for (int i = 0; i < 16; ++i) {
        int node = nl[i];
        xs[i][t] = (node >= 0) ? ld(x, (long)node * 256 + t, f) : 0.f;
    }
    __syncthreads();
    float ak[16], aq[16], av[16];
    #pragma unroll
    for (int i = 0; i < 16; ++i) { ak[i] = 0.f; aq[i] = 0.f; av[i] = 0.f; }
    long wb = (long)tt * 65536;
    auto body = [&](auto ldw) {
        for (int d = 0; d < 256; d += 2) {
            float k0 = ldw(Wk, wb + (d + 0) * 256 + t), k1 = ldw(Wk, wb + (d + 1) * 256 + t);
            float q0 = ldw(Wq, wb + (d + 0) * 256 + t), q1 = ldw(Wq, wb + (d + 1) * 256 + t);
            float v0 = ldw(Wv, wb + (d + 0) * 256 + t), v1 = ldw(Wv, wb + (d + 1) * 256 + t);
            #pragma unroll
            for (int i = 0; i < 16; ++i) {
                float x0 = xs[i][d], x1 = xs[i][d + 1];
                ak[i] += x0 * k0 + x1 * k1;
                aq[i] += x0 * q0 + x1 * q1;
                av[i] += x0 * v0 + x1 * v1;
            }
        }
    };
    if (f) body([](const void* p, long i) { return ((const float*)p)[i]; });
    else   body([](const void* p, long i) { return __bfloat162float(((const bf16*)p)[i]); });
    float bkv = ld(bk, tt * 256 + t, f);
    float bqv = ld(bq, tt * 256 + t, f);
    float bvv = ld(bv, tt * 256 + t, f);
    #pragma unroll
    for (int i = 0; i < 16; ++i) {
        int node = nl[i];
        if (node < 0) break;
        kb[node * 256 + t] = f2us(ak[i] + bkv);
        qb[node * 256 + t] = f2us(aq[i] + bqv);
        vb[node * 256 + t] = f2us(av[i] + bvv);
    }
}

// ---------------- per-r: qrel = rel_att @ q, vrel = rel_msg^T @ v (MFMA) ----------------
// block = 16 nodes; wave = head. C col = node (lane&15), row = out-dim (quad*4+reg).
__global__ __launch_bounds__(256) void relqv(const u16* __restrict__ qb,
        const u16* __restrict__ vb,
        const u16* __restrict__ MTa, const u16* __restrict__ MTm, int r,
        u16* __restrict__ qrel, u16* __restrict__ vrel) {
    int nb = blockIdx.x * 16;
    int t = threadIdx.x, h = t >> 6, lane = t & 63, ln = lane & 15, quad = lane >> 4;
    __shared__ u16 stQ[16][264];
    __shared__ u16 stV[16][264];

    const u16* qp = qb + (size_t)(nb + ln) * 256 + h * 64 + quad * 8;
    const u16* vp = vb + (size_t)(nb + ln) * 256 + h * 64 + quad * 8;
    bf16x8 Bq0 = *(const bf16x8*)(qp);
    bf16x8 Bq1 = *(const bf16x8*)(qp + 32);
    bf16x8 Bv0 = *(const bf16x8*)(vp);
    bf16x8 Bv1 = *(const bf16x8*)(vp + 32);

    long mtbase = (long)(r * HN + h) * 4096;
    #pragma unroll
    for (int mt = 0; mt < 4; ++mt) {
        const u16* ap = MTa + mtbase + (mt * 16 + ln) * 64 + quad * 8;
        const u16* mp = MTm + mtbase + (mt * 16 + ln) * 64 + quad * 8;
        bf16x8 Aa0 = *(const bf16x8*)(ap);
        bf16x8 Aa1 = *(const bf16x8*)(ap + 32);
        bf16x8 Am0 = *(const bf16x8*)(mp);
        bf16x8 Am1 = *(const bf16x8*)(mp + 32);
        f32x4 accQ = {0.f, 0.f, 0.f, 0.f};
        f32x4 accV = {0.f, 0.f, 0.f, 0.f};
        accQ = __builtin_amdgcn_mfma_f32_16x16x32_bf16(Aa0, Bq0, accQ, 0, 0, 0);
        accQ = __builtin_amdgcn_mfma_f32_16x16x32_bf16(Aa1, Bq1, accQ, 0, 0, 0);
        accV = __builtin_amdgcn_mfma_f32_16x16x32_bf16(Am0, Bv0, accV, 0, 0, 0);
        accV = __builtin_amdgcn_mfma_f32_16x16x32_bf16(Am1, Bv1, accV, 0, 0, 0);
        int jc = h * 64 + mt * 16 + quad * 4;
        ushort4 pq, pv;
        pq.x = f2us(accQ[0]); pq.y = f2us(accQ[1]); pq.z = f2us(accQ[2]); pq.w = f2us(accQ[3]);
        pv.x = f2us(accV[0]); pv.y = f2us(accV[1]); pv.z = f2us(accV[2]); pv.w = f2us(accV[3]);
        *(ushort4*)&stQ[ln][jc] = pq;
        *(ushort4*)&stV[ln][jc] = pv;
    }
    __syncthreads();
    #pragma unroll 4
    for (int i = 0; i < 16; ++i) {
        qrel[(size_t)(nb + i) * 256 + t] = stQ[i][t];
        vrel[(size_t)(nb + i) * 256 + t] = stV[i][t];
    }
}

// ---------------- attention for type-r edges: att = k[src]·qrel_r[dst] ----------------
__global__ __launch_bounds__(256) void k2p(const u16* __restrict__ kb,
        const u16* __restrict__ qrel, const void* __restrict__ rel_pri,
        const int* __restrict__ sorted, const int* __restrict__ base,
        const int* __restrict__ esrc, const int* __restrict__ edst,
        const int* __restrict__ flag, int r,
        u16* __restrict__ attex, float* __restrict__ denom) {
    int f = *flag;
    int i = blockIdx.x * 256 + threadIdx.x;
    int rb = base[r * NN], re = base[(r + 1) * NN];
    int ei = i >> 2;
    if (rb + ei >= re) return;
    int h = i & 3;
    int e = sorted[rb + ei];
    int s = esrc[e], dv = edst[e];
    const uint4* kp = (const uint4*)(kb + (size_t)s * 256 + h * 64);
    const uint4* qp = (const uint4*)(qrel + (size_t)dv * 256 + h * 64);
    float dot = 0.f;
    #pragma unroll
    for (int ii = 0; ii < 8; ++ii) {
        uint4 a = kp[ii], b = qp[ii];
        dot += blo(a.x) * blo(b.x) + bhi(a.x) * bhi(b.x);
        dot += blo(a.y) * blo(b.y) + bhi(a.y) * bhi(b.y);
        dot += blo(a.z) * blo(b.z) + bhi(a.z) * bhi(b.z);
        dot += blo(a.w) * blo(b.w) + bhi(a.w) * bhi(b.w);
    }
    float attv = dot * ld(rel_pri, r * HN + h, f) * 0.125f;
    attv = fminf(fmaxf(attv, -50.f), 50.f);
    float ex = expf(attv);
    attex[e * 4 + h] = f2us(ex);
    atomicAdd(&denom[(r * NN + dv) * HN + h], ex);
}

// ---------------- aggregation for type-r edges: block per dst, no atomics ----------------
__global__ __launch_bounds__(256) void k4p(const u16* __restrict__ vrel,
        const u16* __restrict__ attex, const float* __restrict__ denom,
        const int* __restrict__ sorted, const int* __restrict__ base,
        const int* __restrict__ esrc, const int* __restrict__ flag, int r,
        void* __restrict__ tacc) {
    int f = *flag;
    int n = blockIdx.x, t = threadIdx.x, h = t >> 6;
    int seg = r * NN + n;
    int b0 = base[seg], b1 = base[seg + 1];
    long o = (long)n * 256 + t;
    if (b0 == b1) {
        if (r == 0) {
            if (f) ((float*)tacc)[o] = 0.f; else ((u16*)tacc)[o] = 0;
        }
        return;
    }
    float acc = 0.f;
    if (r != 0) acc = f ? ((float*)tacc)[o] : busf(((u16*)tacc)[o]);
    float inv = 1.f / denom[seg * HN + h];
    for (int idx = b0; idx < b1; ++idx) {
        int e = sorted[idx];
        int s = esrc[e];
        float w = busf(attex[e * 4 + h]) * inv;
        acc += w * busf(vrel[(size_t)s * 256 + t]);
    }
    if (f) ((float*)tacc)[o] = acc; else ((u16*)tacc)[o] = f2us(acc);
}

// ---------------- out-linear (bucketed 16 same-type nodes / block) ----------------
__global__ __launch_bounds__(256) void k5a_trans(const void* __restrict__ tacc,
        const int* __restrict__ base,
        const void* __restrict__ Wa, const void* __restrict__ ba,
        const int* __restrict__ lists, const int* __restrict__ cnts,
        const int* __restrict__ flag, u16* __restrict__ trans) {
    int f = *flag;
    int tt = blockIdx.x % TN, tile = blockIdx.x / TN;
    int cntt = cnts[tt];
    int start = tile * 16;
    if (start >= cntt) return;
    __shared__ __align__(16) float xs[16][256];
    __shared__ int nl[16];
    __shared__ float invs[16];
    int t = threadIdx.x;
    if (t < 16) {
        int node = (start + t < cntt) ? lists[tt * NN + start + t] : -1;
        nl[t] = node;
        float iv = 1.f;
        if (node >= 0) {
            int nrel = 0;
            #pragma unroll
            for (int r = 0; r < RN; ++r)
                nrel += (base[r * NN + node + 1] > base[r * NN + node]) ? 1 : 0;
            iv = (nrel > 0) ? 1.f / (float)nrel : 1.f;
        }
        invs[t] = iv;
    }
    __syncthreads();
    #pragma unroll
    for (int i = 0; i < 16; ++i) {
        int node = nl[i];
        float tv = 0.f;
        if (node >= 0) {
            long o = (long)node * 256 + t;
            tv = (f ? ((const float*)tacc)[o] : busf(((const u16*)tacc)[o])) * invs[i];
        }
        xs[i][t] = tv;
    }
    __syncthreads();
    float acc[16];
    #pragma unroll
    for (int i = 0; i < 16; ++i) acc[i] = 0.f;
    long wb = (long)tt * 65536;
    auto body = [&](auto ldw) {
        for (int d = 0; d < 256; d += 2) {
            float w0 = ldw(Wa, wb + (d + 0) * 256 + t);
            float w1 = ldw(Wa, wb + (d + 1) * 256 + t);
            #pragma unroll
            for (int i = 0; i < 16; ++i)
                acc[i] += xs[i][d] * w0 + xs[i][d + 1] * w1;
        }
    };
    if (f) body([](const void* p, long i) { return ((const float*)p)[i]; });
    else   body([](const void* p, long i) { return __bfloat162float(((const bf16*)p)[i]); });
    float bav = ld(ba, tt * 256 + t, f);
    #pragma unroll
    for (int i = 0; i < 16; ++i) {
        int node = nl[i];
        if (node < 0) break;
        trans[(size_t)node * 256 + t] = f2us(acc[i] + bav);
    }
}

// ---------------- skip-gate + LayerNorm + passthrough ----------------
__global__ __launch_bounds__(256) void k5b_ln(const void* __restrict__ x,
        const u16* __restrict__ trans, const void* __restrict__ skip,
        const void* __restrict__ ln_g, const void* __restrict__ ln_b,
        const int* __restrict__ node_type, const int* __restrict__ base,
        const int* __restrict__ flag, void* __restrict__ out) {
    int f = *flag;
    int n = blockIdx.x, t = threadIdx.x;
    int tt = node_type[n];
    __shared__ int has_s;
    if (t == 0) {
        int nrel = 0;
        #pragma unroll
        for (int r = 0; r < RN; ++r)
            nrel += (base[r * NN + n + 1] > base[r * NN + n]) ? 1 : 0;
        has_s = nrel;
    }
    __syncthreads();
    bool has = (has_s > 0);
    float sk = ld(skip, tt, f);
    float alpha = 1.f / (1.f + expf(-sk));
    float xv = ld(x, (long)n * 256 + t, f);
    float outv = busf(trans[(size_t)n * 256 + t]) * alpha + xv * (1.f - alpha);
    __shared__ float r1[256], r2[256];
    r1[t] = outv;
    r2[t] = outv * outv;
    __syncthreads();
    for (int st = 128; st > 0; st >>= 1) {
        if (t < st) { r1[t] += r1[t + st]; r2[t] += r2[t + st]; }
        __syncthreads();
    }
    float mu = r1[0] * (1.f / 256.f);
    float ms = r2[0] * (1.f / 256.f);
    float var = fmaxf(ms - mu * mu, 0.f);
    float normed = (outv - mu) * rsqrtf(var + 1e-5f) * ld(ln_g, tt * 256 + t, f)
                 + ld(ln_b, tt * 256 + t, f);
    float resv = has ? normed : xv;
    if (f) ((float*)out)[(long)n * 256 + t] = resv;
    else   ((bf16*)out)[(long)n * 256 + t] = __float2bfloat16(resv);
}

extern "C" void kernel_launch(void* const* d_in, const int* in_sizes, int n_in,
                              void* d_out, int out_size, void* d_ws, size_t ws_size,
                              hipStream_t stream) {
    const void* x       = d_in[0];
    const void* Wk      = d_in[1];
    const void* bk      = d_in[2];
    const void* Wq      = d_in[3];
    const void* bq      = d_in[4];
    const void* Wv      = d_in[5];
    const void* bv      = d_in[6];
    const void* Wa      = d_in[7];
    const void* ba      = d_in[8];
    const void* rel_pri = d_in[9];
    const void* rel_att = d_in[10];
    const void* rel_msg = d_in[11];
    const void* skip    = d_in[12];
    const void* ln_g    = d_in[13];
    const void* ln_b    = d_in[14];
    const int* node_type = (const int*)d_in[15];
    const int* edge_src  = (const int*)d_in[16];
    const int* edge_dst  = (const int*)d_in[17];
    const int* edge_type = (const int*)d_in[18];
    char* w = (char*)d_ws;

    // layout (bytes) — total 140,994,688 <= proven ws floor 141,000,128
    u16*      kb     = (u16*)(w);                    // 25,600,000 (reused as trans)
    u16*      qb     = (u16*)(w + 25600000);         // 25,600,000
    u16*      vb     = (u16*)(w + 51200000);         // 25,600,000
    u16*      qrel   = (u16*)(w + 76800000);         // 25,600,000 (per-r)
    u16*      vrel   = (u16*)(w + 102400000);        // 25,600,000 (per-r)
    u16*      attex  = (u16*)(w + 128000000);        //  3,200,000 (E*4 bf16)
    int*      sorted = (int*)(w + 131200000);        //  1,600,000
    int*      base   = (int*)(w + 132800000);        //  1,200,064 ((S+1)*4)
    int*      nlists = (int*)(w + 134000064);        //    600,000
    u16*      MTa    = (u16*)(w + 134600064);        //    196,608
    u16*      MTm    = (u16*)(w + 134796672);        //    196,608
    // zero region:
    float*    denom  = (float*)(w + 134993280);      //  4,800,000
    unsigned* cnt    = (unsigned*)(w + 139793280);   //  1,200,000 (reused as cursor)
    int*      ncnts  = (int*)(w + 140993280);        //         64
    int*      flag   = (int*)(w + 140993344);        //         64
    unsigned* csums  = (unsigned*)(w + 140993408);   //      1,280

    hipMemsetAsync(w + 134993280, 0, 6000128, stream);

    detect_dtype<<<dim3(1), dim3(256), 0, stream>>>(x, flag);
    bucket_nodes<<<dim3((NN + 255) / 256), dim3(256), 0, stream>>>(node_type, nlists, ncnts);
    count_seg<<<dim3((EE + 255) / 256), dim3(256), 0, stream>>>(edge_dst, edge_type, cnt);
    scanA<<<dim3(NCHUNK), dim3(256), 0, stream>>>(cnt, csums);
    scanB<<<dim3(1), dim3(256), 0, stream>>>(csums, base);
    scanC<<<dim3(NCHUNK), dim3(256), 0, stream>>>(cnt, csums, base);
    scatter_edges<<<dim3((EE + 255) / 256), dim3(256), 0, stream>>>(
        edge_dst, edge_type, base, cnt, sorted);
    transM<<<dim3(48), dim3(256), 0, stream>>>(rel_att, rel_msg, flag, MTa, MTm);
    k1_kqv<<<dim3(TN * (NN / 16)), dim3(256), 0, stream>>>(
        x, Wk, bk, Wq, bq, Wv, bv, nlists, ncnts, flag, kb, qb, vb);

    for (int r = 0; r < RN; ++r) {
        relqv<<<dim3(NN / 16), dim3(256), 0, stream>>>(qb, vb, MTa, MTm, r, qrel, vrel);
        k2p<<<dim3(EE * HN / 256), dim3(256), 0, stream>>>(
            kb, qrel, rel_pri, sorted, base, edge_src, edge_dst, flag, r, attex, denom);
        k4p<<<dim3(NN), dim3(256), 0, stream>>>(
            vrel, attex, denom, sorted, base, edge_src, flag, r, d_out);
    }

    k5a_trans<<<dim3(TN * (NN / 16)), dim3(256), 0, stream>>>(
        d_out, base, Wa, ba, nlists, ncnts, flag, kb /*trans*/);
    k5b_ln<<<dim3(NN), dim3(256), 0, stream>>>(
        x, kb /*trans*/, skip, ln_g, ln_b, node_type, base, flag, d_out);
}

// Round 6
// 950.546 us; speedup vs baseline: 3.5610x; 1.4208x over previous
//
#include <hip/hip_runtime.h>
#include <hip/hip_bf16.h>

// HGT layer: N=50000, E=400000, D=256, T=3, R=6, H=4, DK=64.
// Round 5: k1 and k5 on MFMA (WallT/WaT pre-transposed), k5a+k5b fused with LN,
// k2p+k4p fused per relation (LDS att/denom, wave-per-dst aggregation).

#define NN 50000
#define EE 400000
#define TN 3
#define RN 6
#define HN 4
#define SS (NN * RN)
#define NCHUNK 293   // ceil(SS/1024)
#define CD 32        // dsts per k2k4 block

typedef __hip_bfloat16 bf16;
typedef unsigned short u16;
using bf16x8 = __attribute__((ext_vector_type(8))) __bf16;
using f32x4  = __attribute__((ext_vector_type(4))) float;

__device__ __forceinline__ float b2f(bf16 h) { return __bfloat162float(h); }
__device__ __forceinline__ float busf(u16 u) { return __uint_as_float((unsigned)u << 16); }
__device__ __forceinline__ float blo(unsigned u) { return __uint_as_float(u << 16); }
__device__ __forceinline__ float bhi(unsigned u) { return __uint_as_float(u & 0xffff0000u); }
__device__ __forceinline__ u16 f2us(float f) {   // f32 -> bf16 bits, RNE
    unsigned u = __float_as_uint(f);
    return (u16)((u + 0x7fffu + ((u >> 16) & 1u)) >> 16);
}
__device__ __forceinline__ float ld(const void* p, long i, int f) {
    return f ? ((const float*)p)[i] : b2f(((const bf16*)p)[i]);
}

// ---------------- input dtype sniffer (f32 vs bf16 buffers) ----------------
__global__ __launch_bounds__(256) void detect_dtype(const void* __restrict__ x,
                                                    int* __restrict__ flag) {
    __shared__ int cnt_s;
    if (threadIdx.x == 0) cnt_s = 0;
    __syncthreads();
    const u16* p = (const u16*)x;
    int c = 0;
    for (int i = threadIdx.x; i < 8192; i += 256) {
        int expo = (p[i] >> 7) & 0xFF;
        if (expo >= 0x97) ++c;
    }
    atomicAdd(&cnt_s, c);
    __syncthreads();
    if (threadIdx.x == 0) *flag = (cnt_s > 64) ? 1 : 0;
}

// ---------------- bucket nodes by type ----------------
__global__ __launch_bounds__(256) void bucket_nodes(const int* __restrict__ node_type,
                                                    int* __restrict__ lists,
                                                    int* __restrict__ cnts) {
    __shared__ int lc[TN], lbase[TN];
    int t = threadIdx.x;
    if (t < TN) lc[t] = 0;
    __syncthreads();
    int n = blockIdx.x * 256 + t;
    int pos = -1, ty = 0;
    if (n < NN) {
        ty = node_type[n];
        pos = atomicAdd(&lc[ty], 1);
    }
    __syncthreads();
    if (t < TN) lbase[t] = atomicAdd(&cnts[t], lc[t]);
    __syncthreads();
    if (n < NN) lists[ty * NN + lbase[ty] + pos] = n;
}

// ---------------- per-(r,dst) segment edge counts ----------------
__global__ __launch_bounds__(256) void count_seg(const int* __restrict__ edst,
        const int* __restrict__ etype, unsigned* __restrict__ cnt) {
    int e = blockIdx.x * 256 + threadIdx.x;
    if (e >= EE) return;
    atomicAdd(&cnt[etype[e] * NN + edst[e]], 1u);
}

// ---------------- 3-phase exclusive scan over SS segments ----------------
__global__ __launch_bounds__(256) void scanA(const unsigned* __restrict__ cnt,
                                             unsigned* __restrict__ csums) {
    __shared__ unsigned s[256];
    int b = blockIdx.x, t = threadIdx.x;
    int s0 = b * 1024 + t * 4;
    unsigned v = 0;
    if (s0 + 3 < SS) { uint4 u = *(const uint4*)&cnt[s0]; v = u.x + u.y + u.z + u.w; }
    else { for (int j = 0; j < 4; ++j) if (s0 + j < SS) v += cnt[s0 + j]; }
    s[t] = v;
    __syncthreads();
    for (int st = 128; st > 0; st >>= 1) {
        if (t < st) s[t] += s[t + st];
        __syncthreads();
    }
    if (t == 0) csums[b] = s[0];
}

__global__ __launch_bounds__(256) void scanB(unsigned* __restrict__ csums,
                                             int* __restrict__ base) {
    __shared__ unsigned s[512];
    int t = threadIdx.x;
    unsigned a = (t < NCHUNK) ? csums[t] : 0u;
    unsigned b = (256 + t < NCHUNK) ? csums[256 + t] : 0u;
    s[t] = a; s[256 + t] = b;
    __syncthreads();
    for (int st = 1; st < 512; st <<= 1) {
        unsigned x0 = (t >= st) ? s[t - st] : 0u;
        unsigned x1 = (256 + t >= st) ? s[256 + t - st] : 0u;
        __syncthreads();
        s[t] += x0; s[256 + t] += x1;
        __syncthreads();
    }
    if (t < NCHUNK) csums[t] = s[t] - a;
    if (256 + t < NCHUNK) csums[256 + t] = s[256 + t] - b;
    if (t == 0) base[SS] = (int)s[NCHUNK - 1];
}

__global__ __launch_bounds__(256) void scanC(const unsigned* __restrict__ cnt,
        const unsigned* __restrict__ csums, int* __restrict__ base) {
    __shared__ unsigned s[256];
    int b = blockIdx.x, t = threadIdx.x;
    int s0 = b * 1024 + t * 4;
    unsigned vs[4] = {0u, 0u, 0u, 0u};
    if (s0 + 3 < SS) { uint4 u = *(const uint4*)&cnt[s0]; vs[0]=u.x; vs[1]=u.y; vs[2]=u.z; vs[3]=u.w; }
    else { for (int j = 0; j < 4; ++j) if (s0 + j < SS) vs[j] = cnt[s0 + j]; }
    unsigned v = vs[0] + vs[1] + vs[2] + vs[3];
    s[t] = v;
    __syncthreads();
    for (int st = 1; st < 256; st <<= 1) {
        unsigned x = (t >= st) ? s[t - st] : 0u;
        __syncthreads();
        s[t] += x;
        __syncthreads();
    }
    unsigned run = csums[b] + s[t] - v;
    for (int j = 0; j < 4; ++j) {
        if (s0 + j < SS) { base[s0 + j] = (int)run; run += vs[j]; }
    }
}

// ---------------- scatter edges into seg-sorted order (consumes cnt) ----------------
__global__ __launch_bounds__(256) void scatter_edges(const int* __restrict__ edst,
        const int* __restrict__ etype, const int* __restrict__ base,
        unsigned* __restrict__ cnt, int* __restrict__ sorted) {
    int e = blockIdx.x * 256 + threadIdx.x;
    if (e >= EE) return;
    int seg = etype[e] * NN + edst[e];
    unsigned old = atomicSub(&cnt[seg], 1u);
    sorted[base[seg] + (int)old - 1] = e;
}

// ---------------- rel_att -> bf16 copy (MTa), rel_msg -> bf16 transpose (MTm) ----------------
__global__ __launch_bounds__(256) void transM(const void* __restrict__ rel_att,
        const void* __restrict__ rel_msg, const int* __restrict__ flag,
        u16* __restrict__ MTa, u16* __restrict__ MTm) {
    int f = *flag;
    int m = blockIdx.x;                 // 0..23 att copy, 24..47 msg transpose
    long base = (long)(m % 24) * 4096;
    if (m < 24) {
        for (int it = 0; it < 16; ++it) {
            int idx = it * 256 + threadIdx.x;
            MTa[base + idx] = f2us(ld(rel_att, base + idx, f));
        }
    } else {
        for (int it = 0; it < 16; ++it) {
            int idx = it * 256 + threadIdx.x;
            int d = idx >> 6, j = idx & 63;
            MTm[base + (j << 6) + d] = f2us(ld(rel_msg, base + idx, f));
        }
    }
}

// ---------------- transpose Wk/Wq/Wv -> WallT[t][768][256], Wa -> WaT[t][256][256] ----------------
__global__ __launch_bounds__(256) void transW(const void* __restrict__ Wk,
        const void* __restrict__ Wq, const void* __restrict__ Wv,
        const void* __restrict__ Wa, const int* __restrict__ flag,
        u16* __restrict__ WallT, u16* __restrict__ WaT) {
    int f = *flag;
    int m = blockIdx.x;   // 0..2303 -> WallT rows, 2304..3071 -> WaT rows
    int t = threadIdx.x;  // = d
    if (m < 2304) {
        int ty = m / 768, o3 = m % 768;
        int sec = o3 >> 8, o = o3 & 255;
        const void* W = (sec == 0) ? Wk : (sec == 1) ? Wq : Wv;
        WallT[(size_t)ty * 768 * 256 + (size_t)o3 * 256 + t] =
            f2us(ld(W, (long)ty * 65536 + (long)t * 256 + o, f));
    } else {
        int mm = m - 2304;
        int ty = mm / 256, o = mm % 256;
        WaT[(size_t)ty * 65536 + (size_t)o * 256 + t] =
            f2us(ld(Wa, (long)ty * 65536 + (long)t * 256 + o, f));
    }
}

// ---------------- x -> bf16 ----------------
__global__ __launch_bounds__(256) void convertX(const void* __restrict__ x,
        const int* __restrict__ flag, u16* __restrict__ xb) {
    int f = *flag;
    long i = ((long)blockIdx.x * 256 + threadIdx.x) * 4;
    if (i >= (long)NN * 256) return;
    if (f) {
        float4 v = *(const float4*)((const float*)x + i);
        ushort4 p; p.x = f2us(v.x); p.y = f2us(v.y); p.z = f2us(v.z); p.w = f2us(v.w);
        *(ushort4*)(xb + i) = p;
    } else {
        *(ushort4*)(xb + i) = *(const ushort4*)((const u16*)x + i);
    }
}

// ---------------- k/q/v typed linear via MFMA (16 same-type nodes / block) ----------------
__global__ __launch_bounds__(256) void k1_mfma(const u16* __restrict__ xb,
        const u16* __restrict__ WallT,
        const void* __restrict__ bk, const void* __restrict__ bq,
        const void* __restrict__ bv,
        const int* __restrict__ lists, const int* __restrict__ cnts,
        const int* __restrict__ flag,
        u16* __restrict__ kb, u16* __restrict__ qb, u16* __restrict__ vb) {
    int f = *flag;
    int tt = blockIdx.x % TN, tile = blockIdx.x / TN;
    int cnt = cnts[tt];
    int start = tile * 16;
    if (start >= cnt) return;
    __shared__ int nl[16];
    __shared__ __align__(16) u16 xs[16][280];   // 560B stride: 16B-aligned, 2-way banks
    __shared__ __align__(16) u16 st[16][776];
    int t = threadIdx.x;
    if (t < 16) nl[t] = (start + t < cnt) ? lists[tt * NN + start + t] : -1;
    __syncthreads();
    {
        int i = t >> 4, g = t & 15;
        int node = nl[i];
        uint4 a = {0, 0, 0, 0}, b = {0, 0, 0, 0};
        if (node >= 0) {
            const uint4* src = (const uint4*)(xb + (size_t)node * 256 + g * 16);
            a = src[0]; b = src[1];
        }
        *(uint4*)&xs[i][g * 16] = a;
        *(uint4*)&xs[i][g * 16 + 8] = b;
    }
    __syncthreads();
    int w = t >> 6, lane = t & 63, ln = lane & 15, quad = lane >> 4;
    const u16* Wt = WallT + (size_t)tt * 768 * 256;
    f32x4 acc[12];
    #pragma unroll
    for (int j = 0; j < 12; ++j) acc[j] = (f32x4){0.f, 0.f, 0.f, 0.f};
    #pragma unroll
    for (int kt = 0; kt < 8; ++kt) {
        bf16x8 B = *(const bf16x8*)&xs[ln][kt * 32 + quad * 8];
        #pragma unroll
        for (int jt = 0; jt < 12; ++jt) {
            int jg = w * 192 + jt * 16 + ln;
            bf16x8 A = *(const bf16x8*)(Wt + (size_t)jg * 256 + kt * 32 + quad * 8);
            acc[jt] = __builtin_amdgcn_mfma_f32_16x16x32_bf16(A, B, acc[jt], 0, 0, 0);
        }
    }
    #pragma unroll
    for (int jt = 0; jt < 12; ++jt) {
        int jc = w * 192 + jt * 16 + quad * 4;
        ushort4 p;
        p.x = f2us(acc[jt][0]); p.y = f2us(acc[jt][1]);
        p.z = f2us(acc[jt][2]); p.w = f2us(acc[jt][3]);
        *(ushort4*)&st[ln][jc] = p;
    }
    __syncthreads();
    float bkv = ld(bk, tt * 256 + t, f);
    float bqv = ld(bq, tt * 256 + t, f);
    float bvv = ld(bv, tt * 256 + t, f);
    for (int i = 0; i < 16; ++i) {
        int node = nl[i];
        if (node < 0) break;
        size_t o = (size_t)node * 256 + t;
        kb[o] = f2us(busf(st[i][t])       + bkv);
        qb[o] = f2us(busf(st[i][256 + t]) + bqv);
        vb[o] = f2us(busf(st[i][512 + t]) + bvv);
    }
}

// ---------------- per-r: qrel = rel_att @ q, vrel = rel_msg^T @ v (MFMA) ----------------
__global__ __launch_bounds__(256) void relqv(const u16* __restrict__ qb,
        const u16* __restrict__ vb,
        const u16* __restrict__ MTa, const u16* __restrict__ MTm, int r,
        u16* __restrict__ qrel, u16* __restrict__ vrel) {
    int nb = blockIdx.x * 16;
    int t = threadIdx.x, h = t >> 6, lane = t & 63, ln = lane & 15, quad = lane >> 4;
    __shared__ u16 stQ[16][264];
    __shared__ u16 stV[16][264];

    const u16* qp = qb + (size_t)(nb + ln) * 256 + h * 64 + quad * 8;
    const u16* vp = vb + (size_t)(nb + ln) * 256 + h * 64 + quad * 8;
    bf16x8 Bq0 = *(const bf16x8*)(qp);
    bf16x8 Bq1 = *(const bf16x8*)(qp + 32);
    bf16x8 Bv0 = *(const bf16x8*)(vp);
    bf16x8 Bv1 = *(const bf16x8*)(vp + 32);

    long mtbase = (long)(r * HN + h) * 4096;
    #pragma unroll
    for (int mt = 0; mt < 4; ++mt) {
        const u16* ap = MTa + mtbase + (mt * 16 + ln) * 64 + quad * 8;
        const u16* mp = MTm + mtbase + (mt * 16 + ln) * 64 + quad * 8;
        bf16x8 Aa0 = *(const bf16x8*)(ap);
        bf16x8 Aa1 = *(const bf16x8*)(ap + 32);
        bf16x8 Am0 = *(const bf16x8*)(mp);
        bf16x8 Am1 = *(const bf16x8*)(mp + 32);
        f32x4 accQ = {0.f, 0.f, 0.f, 0.f};
        f32x4 accV = {0.f, 0.f, 0.f, 0.f};
        accQ = __builtin_amdgcn_mfma_f32_16x16x32_bf16(Aa0, Bq0, accQ, 0, 0, 0);
        accQ = __builtin_amdgcn_mfma_f32_16x16x32_bf16(Aa1, Bq1, accQ, 0, 0, 0);
        accV = __builtin_amdgcn_mfma_f32_16x16x32_bf16(Am0, Bv0, accV, 0, 0, 0);
        accV = __builtin_amdgcn_mfma_f32_16x16x32_bf16(Am1, Bv1, accV, 0, 0, 0);
        int jc = h * 64 + mt * 16 + quad * 4;
        ushort4 pq, pv;
        pq.x = f2us(accQ[0]); pq.y = f2us(accQ[1]); pq.z = f2us(accQ[2]); pq.w = f2us(accQ[3]);
        pv.x = f2us(accV[0]); pv.y = f2us(accV[1]); pv.z = f2us(accV[2]); pv.w = f2us(accV[3]);
        *(ushort4*)&stQ[ln][jc] = pq;
        *(ushort4*)&stV[ln][jc] = pv;
    }
    __syncthreads();
    #pragma unroll 4
    for (int i = 0; i < 16; ++i) {
        qrel[(size_t)(nb + i) * 256 + t] = stQ[i][t];
        vrel[(size_t)(nb + i) * 256 + t] = stV[i][t];
    }
}

// ---------------- fused attention + aggregation for relation r ----------------
// block = CD consecutive dsts; edges contiguous in sorted[].
__global__ __launch_bounds__(256) void k2k4(const u16* __restrict__ kb,
        const u16* __restrict__ qrel, const u16* __restrict__ vrel,
        const void* __restrict__ rel_pri,
        const int* __restrict__ sorted, const int* __restrict__ base,
        const int* __restrict__ esrc, const int* __restrict__ edst,
        const int* __restrict__ flag, int r,
        u16* __restrict__ attex_g, void* tacc) {
    int f = *flag;
    int c0 = blockIdx.x * CD;
    int nd = min(CD, NN - c0);
    int segb = r * NN + c0;
    __shared__ float attL[1280];
    __shared__ float denomL[CD * HN];
    __shared__ int sb_[CD + 1];
    int t = threadIdx.x;
    if (t < CD * HN) denomL[t] = 0.f;
    if (t <= nd) sb_[t] = base[segb + t];
    __syncthreads();
    int b0 = sb_[0], b1 = sb_[nd];
    int nE = b1 - b0;
    // phase A: att logits -> exp (thread per edge-head)
    for (int i = t; i < nE * 4; i += 256) {
        int e = sorted[b0 + (i >> 2)];
        int h = i & 3;
        int s = esrc[e], dv = edst[e];
        const uint4* kp = (const uint4*)(kb + (size_t)s * 256 + h * 64);
        const uint4* qp = (const uint4*)(qrel + (size_t)dv * 256 + h * 64);
        float dot = 0.f;
        #pragma unroll
        for (int ii = 0; ii < 8; ++ii) {
            uint4 a = kp[ii], b = qp[ii];
            dot += blo(a.x) * blo(b.x) + bhi(a.x) * bhi(b.x);
            dot += blo(a.y) * blo(b.y) + bhi(a.y) * bhi(b.y);
            dot += blo(a.z) * blo(b.z) + bhi(a.z) * bhi(b.z);
            dot += blo(a.w) * blo(b.w) + bhi(a.w) * bhi(b.w);
        }
        float attv = dot * ld(rel_pri, r * HN + h, f) * 0.125f;
        attv = fminf(fmaxf(attv, -50.f), 50.f);
        float ex = expf(attv);
        if (i < 1280) attL[i] = ex;
        else attex_g[(size_t)b0 * 4 + i] = f2us(ex);   // statistical never-path
        atomicAdd(&denomL[(dv - c0) * HN + h], ex);
    }
    __syncthreads();
    // phase B: wave per dst, lane dd covers dims dd*4..dd*4+3 (head dd>>4)
    int w = t >> 6, lane = t & 63;
    for (int i = w; i < nd; i += 4) {
        int sb = sb_[i], se = sb_[i + 1];
        long o = (long)(c0 + i) * 256 + lane * 4;
        if (se == sb) {
            if (r == 0) {
                if (f) { float4 z = {0.f, 0.f, 0.f, 0.f}; *(float4*)((float*)tacc + o) = z; }
                else   { ushort4 z = {0, 0, 0, 0}; *(ushort4*)((u16*)tacc + o) = z; }
            }
            continue;
        }
        float a0 = 0.f, a1 = 0.f, a2 = 0.f, a3 = 0.f;
        if (r != 0) {
            if (f) { float4 v = *(const float4*)((const float*)tacc + o);
                     a0 = v.x; a1 = v.y; a2 = v.z; a3 = v.w; }
            else   { ushort4 v = *(const ushort4*)((const u16*)tacc + o);
                     a0 = busf(v.x); a1 = busf(v.y); a2 = busf(v.z); a3 = busf(v.w); }
        }
        int h = lane >> 4;
        float inv = 1.f / denomL[i * HN + h];
        for (int idx = sb; idx < se; ++idx) {
            int li = (idx - b0) * 4 + h;
            float wgt = ((li < 1280) ? attL[li] : busf(attex_g[(size_t)idx * 4 + h])) * inv;
            int s = esrc[sorted[idx]];
            ushort4 v = *(const ushort4*)(vrel + (size_t)s * 256 + lane * 4);
            a0 += wgt * busf(v.x); a1 += wgt * busf(v.y);
            a2 += wgt * busf(v.z); a3 += wgt * busf(v.w);
        }
        if (f) { float4 v = {a0, a1, a2, a3}; *(float4*)((float*)tacc + o) = v; }
        else   { ushort4 v; v.x = f2us(a0); v.y = f2us(a1); v.z = f2us(a2); v.w = f2us(a3);
                 *(ushort4*)((u16*)tacc + o) = v; }
    }
}

// ---------------- fused out-linear (MFMA) + skip-gate + LayerNorm ----------------
__global__ __launch_bounds__(256) void k5_fused(const void* __restrict__ x,
        const void* tacc, const u16* __restrict__ WaT,
        const void* __restrict__ ba, const void* __restrict__ skip,
        const void* __restrict__ ln_g, const void* __restrict__ ln_b,
        const int* __restrict__ base,
        const int* __restrict__ lists, const int* __restrict__ cnts,
        const int* __restrict__ flag, void* out) {
    int f = *flag;
    int tt = blockIdx.x % TN, tile = blockIdx.x / TN;
    int cnt = cnts[tt];
    int start = tile * 16;
    if (start >= cnt) return;
    __shared__ int nl[16];
    __shared__ float invs[16];
    __shared__ int hasv[16];
    __shared__ __align__(16) u16 xs[16][280];
    __shared__ __align__(16) float st[16][264];
    __shared__ float red1[256], red2[256];
    __shared__ float mu_[16], rs_[16];
    int t = threadIdx.x;
    if (t < 16) {
        int node = (start + t < cnt) ? lists[tt * NN + start + t] : -1;
        nl[t] = node;
        int nrel = 0;
        if (node >= 0) {
            #pragma unroll
            for (int r = 0; r < RN; ++r)
                nrel += (base[r * NN + node + 1] > base[r * NN + node]) ? 1 : 0;
        }
        hasv[t] = nrel;
        invs[t] = (nrel > 0) ? 1.f / (float)nrel : 1.f;
    }
    __syncthreads();
    {
        int i = t >> 4, g = t & 15;
        int node = nl[i];
        float inv = invs[i];
        u16 buf[16];
        if (node >= 0) {
            long o = (long)node * 256 + g * 16;
            if (f) {
                const float* src = (const float*)tacc + o;
                #pragma unroll
                for (int j = 0; j < 16; ++j) buf[j] = f2us(src[j] * inv);
            } else {
                const u16* src = (const u16*)tacc + o;
                #pragma unroll
                for (int j = 0; j < 16; ++j) buf[j] = f2us(busf(src[j]) * inv);
            }
        } else {
            #pragma unroll
            for (int j = 0; j < 16; ++j) buf[j] = 0;
        }
        #pragma unroll
        for (int j = 0; j < 16; ++j) xs[i][g * 16 + j] = buf[j];
    }
    __syncthreads();
    int w = t >> 6, lane = t & 63, ln = lane & 15, quad = lane >> 4;
    const u16* Wt = WaT + (size_t)tt * 65536;
    f32x4 acc[4];
    #pragma unroll
    for (int j = 0; j < 4; ++j) acc[j] = (f32x4){0.f, 0.f, 0.f, 0.f};
    #pragma unroll
    for (int kt = 0; kt < 8; ++kt) {
        bf16x8 B = *(const bf16x8*)&xs[ln][kt * 32 + quad * 8];
        #pragma unroll
        for (int jt = 0; jt < 4; ++jt) {
            int jg = w * 64 + jt * 16 + ln;
            bf16x8 A = *(const bf16x8*)(Wt + (size_t)jg * 256 + kt * 32 + quad * 8);
            acc[jt] = __builtin_amdgcn_mfma_f32_16x16x32_bf16(A, B, acc[jt], 0, 0, 0);
        }
    }
    #pragma unroll
    for (int jt = 0; jt < 4; ++jt) {
        int jc = w * 64 + jt * 16 + quad * 4;
        #pragma unroll
        for (int rg = 0; rg < 4; ++rg)
            st[ln][jc + rg] = acc[jt][rg] + ld(ba, tt * 256 + jc + rg, f);
    }
    __syncthreads();
    float sk = ld(skip, tt, f);
    float alpha = 1.f / (1.f + expf(-sk));
    {
        int i = t >> 4, g = t & 15;
        int node = nl[i];
        float p1 = 0.f, p2 = 0.f;
        if (node >= 0) {
            #pragma unroll
            for (int j = 0; j < 16; ++j) {
                int o = g * 16 + j;
                float xv = ld(x, (long)node * 256 + o, f);
                float ov = st[i][o] * alpha + xv * (1.f - alpha);
                st[i][o] = ov;
                p1 += ov; p2 += ov * ov;
            }
        }
        red1[t] = p1; red2[t] = p2;
    }
    __syncthreads();
    for (int s = 8; s > 0; s >>= 1) {
        if ((t & 15) < s) { red1[t] += red1[t + s]; red2[t] += red2[t + s]; }
        __syncthreads();
    }
    if ((t & 15) == 0) {
        int i = t >> 4;
        float mu = red1[t] * (1.f / 256.f);
        float ms = red2[t] * (1.f / 256.f);
        float var = fmaxf(ms - mu * mu, 0.f);
        mu_[i] = mu; rs_[i] = rsqrtf(var + 1e-5f);
    }
    __syncthreads();
    float g_ = ld(ln_g, tt * 256 + t, f);
    float b_ = ld(ln_b, tt * 256 + t, f);
    for (int i = 0; i < 16; ++i) {
        int node = nl[i];
        if (node < 0) break;
        float resv;
        if (hasv[i] > 0) resv = (st[i][t] - mu_[i]) * rs_[i] * g_ + b_;
        else             resv = ld(x, (long)node * 256 + t, f);
        if (f) ((float*)out)[(long)node * 256 + t] = resv;
        else   ((u16*)out)[(long)node * 256 + t] = f2us(resv);
    }
}

extern "C" void kernel_launch(void* const* d_in, const int* in_sizes, int n_in,
                              void* d_out, int out_size, void* d_ws, size_t ws_size,
                              hipStream_t stream) {
    const void* x       = d_in[0];
    const void* Wk      = d_in[1];
    const void* bk      = d_in[2];
    const void* Wq      = d_in[3];
    const void* bq      = d_in[4];
    const void* Wv      = d_in[5];
    const void* bv      = d_in[6];
    const void* Wa      = d_in[7];
    const void* ba      = d_in[8];
    const void* rel_pri = d_in[9];
    const void* rel_att = d_in[10];
    const void* rel_msg = d_in[11];
    const void* skip    = d_in[12];
    const void* ln_g    = d_in[13];
    const void* ln_b    = d_in[14];
    const int* node_type = (const int*)d_in[15];
    const int* edge_src  = (const int*)d_in[16];
    const int* edge_dst  = (const int*)d_in[17];
    const int* edge_type = (const int*)d_in[18];
    char* w = (char*)d_ws;

    // layout (bytes) — total 137,767,552 <= proven ws floor 141,000,128
    u16*      kb     = (u16*)(w);                    // 25,600,000
    u16*      qb     = (u16*)(w + 25600000);         // 25,600,000
    u16*      vb     = (u16*)(w + 51200000);         // 25,600,000
    u16*      qrel   = (u16*)(w + 76800000);         // 25,600,000 (xb before r-loop)
    u16*      xb     = (u16*)(w + 76800000);         //   overlay
    u16*      vrel   = (u16*)(w + 102400000);        // 25,600,000
    u16*      attex  = (u16*)(w + 128000000);        //  3,200,000
    int*      sorted = (int*)(w + 131200000);        //  1,600,000
    int*      base   = (int*)(w + 132800000);        //  1,200,064
    int*      nlists = (int*)(w + 134000064);        //    600,000
    u16*      MTa    = (u16*)(w + 134600064);        //    196,608
    u16*      MTm    = (u16*)(w + 134796672);        //    196,608
    u16*      WallT  = (u16*)(w + 134993280);        //  1,179,648
    u16*      WaT    = (u16*)(w + 136172928);        //    393,216
    // zero region:
    unsigned* cnt    = (unsigned*)(w + 136566144);   //  1,200,000
    int*      ncnts  = (int*)(w + 137766144);        //         64
    int*      flag   = (int*)(w + 137766208);        //         64
    unsigned* csums  = (unsigned*)(w + 137766272);   //      1,280

    hipMemsetAsync(w + 136566144, 0, 1201408, stream);

    detect_dtype<<<dim3(1), dim3(256), 0, stream>>>(x, flag);
    bucket_nodes<<<dim3((NN + 255) / 256), dim3(256), 0, stream>>>(node_type, nlists, ncnts);
    count_seg<<<dim3((EE + 255) / 256), dim3(256), 0, stream>>>(edge_dst, edge_type, cnt);
    scanA<<<dim3(NCHUNK), dim3(256), 0, stream>>>(cnt, csums);
    scanB<<<dim3(1), dim3(256), 0, stream>>>(csums, base);
    scanC<<<dim3(NCHUNK), dim3(256), 0, stream>>>(cnt, csums, base);
    scatter_edges<<<dim3((EE + 255) / 256), dim3(256), 0, stream>>>(
        edge_dst, edge_type, base, cnt, sorted);
    transM<<<dim3(48), dim3(256), 0, stream>>>(rel_att, rel_msg, flag, MTa, MTm);
    transW<<<dim3(3072), dim3(256), 0, stream>>>(Wk, Wq, Wv, Wa, flag, WallT, WaT);
    convertX<<<dim3((NN * 256 / 4 + 255) / 256), dim3(256), 0, stream>>>(x, flag, xb);

    k1_mfma<<<dim3(TN * (NN / 16)), dim3(256), 0, stream>>>(
        xb, WallT, bk, bq, bv, nlists, ncnts, flag, kb, qb, vb);

    for (int r = 0; r < RN; ++r) {
        relqv<<<dim3(NN / 16), dim3(256), 0, stream>>>(qb, vb, MTa, MTm, r, qrel, vrel);
        k2k4<<<dim3((NN + CD - 1) / CD), dim3(256), 0, stream>>>(
            kb, qrel, vrel, rel_pri, sorted, base, edge_src, edge_dst, flag, r,
            attex, d_out);
    }

    k5_fused<<<dim3(TN * (NN / 16)), dim3(256), 0, stream>>>(
        x, d_out, WaT, ba, skip, ln_g, ln_b, base, nlists, ncnts, flag, d_out);
}

// Round 7
// 827.335 us; speedup vs baseline: 4.0913x; 1.1489x over previous
//
#include <hip/hip_runtime.h>
#include <hip/hip_bf16.h>

// HGT layer: N=50000, E=400000, D=256, T=3, R=6, H=4, DK=64.
// Round 6: k1 latency fix (launch_bounds 256,2 + batched A-frag loads + 32-node
// tiles + LDS overlay), k5 A-batching, k2k4 srcL cache, merged prep kernel.

#define NN 50000
#define EE 400000
#define TN 3
#define RN 6
#define HN 4
#define SS (NN * RN)
#define NCHUNK 293   // ceil(SS/1024)
#define CD 32        // dsts per k2k4 block

typedef __hip_bfloat16 bf16;
typedef unsigned short u16;
using bf16x8 = __attribute__((ext_vector_type(8))) __bf16;
using f32x4  = __attribute__((ext_vector_type(4))) float;

__device__ __forceinline__ float b2f(bf16 h) { return __bfloat162float(h); }
__device__ __forceinline__ float busf(u16 u) { return __uint_as_float((unsigned)u << 16); }
__device__ __forceinline__ float blo(unsigned u) { return __uint_as_float(u << 16); }
__device__ __forceinline__ float bhi(unsigned u) { return __uint_as_float(u & 0xffff0000u); }
__device__ __forceinline__ u16 f2us(float f) {   // f32 -> bf16 bits, RNE
    unsigned u = __float_as_uint(f);
    return (u16)((u + 0x7fffu + ((u >> 16) & 1u)) >> 16);
}
__device__ __forceinline__ float ld(const void* p, long i, int f) {
    return f ? ((const float*)p)[i] : b2f(((const bf16*)p)[i]);
}

// ---------------- input dtype sniffer (f32 vs bf16 buffers) ----------------
__global__ __launch_bounds__(256) void detect_dtype(const void* __restrict__ x,
                                                    int* __restrict__ flag) {
    __shared__ int cnt_s;
    if (threadIdx.x == 0) cnt_s = 0;
    __syncthreads();
    const u16* p = (const u16*)x;
    int c = 0;
    for (int i = threadIdx.x; i < 8192; i += 256) {
        int expo = (p[i] >> 7) & 0xFF;
        if (expo >= 0x97) ++c;
    }
    atomicAdd(&cnt_s, c);
    __syncthreads();
    if (threadIdx.x == 0) *flag = (cnt_s > 64) ? 1 : 0;
}

// ---------------- merged prep: transM + transW + convertX + bucket + count ----------------
__global__ __launch_bounds__(256) void prep(const void* __restrict__ rel_att,
        const void* __restrict__ rel_msg,
        const void* __restrict__ Wk, const void* __restrict__ Wq,
        const void* __restrict__ Wv, const void* __restrict__ Wa,
        const void* __restrict__ x, const int* __restrict__ node_type,
        const int* __restrict__ edst, const int* __restrict__ etype,
        const int* __restrict__ flag,
        u16* __restrict__ MTa, u16* __restrict__ MTm,
        u16* __restrict__ WallT, u16* __restrict__ WaT,
        u16* __restrict__ xb,
        int* __restrict__ lists, int* __restrict__ cnts,
        unsigned* __restrict__ cnt) {
    int b = blockIdx.x;
    int t = threadIdx.x;
    if (b < 48) {
        int f = *flag;
        int m = b;                 // 0..23 att copy, 24..47 msg transpose
        long base = (long)(m % 24) * 4096;
        if (m < 24) {
            for (int it = 0; it < 16; ++it) {
                int idx = it * 256 + t;
                MTa[base + idx] = f2us(ld(rel_att, base + idx, f));
            }
        } else {
            for (int it = 0; it < 16; ++it) {
                int idx = it * 256 + t;
                int d = idx >> 6, j = idx & 63;
                MTm[base + (j << 6) + d] = f2us(ld(rel_msg, base + idx, f));
            }
        }
    } else if (b < 3120) {
        int f = *flag;
        int m = b - 48;            // 0..2303 WallT rows, 2304..3071 WaT rows
        if (m < 2304) {
            int ty = m / 768, o3 = m % 768;
            int sec = o3 >> 8, o = o3 & 255;
            const void* W = (sec == 0) ? Wk : (sec == 1) ? Wq : Wv;
            WallT[(size_t)ty * 768 * 256 + (size_t)o3 * 256 + t] =
                f2us(ld(W, (long)ty * 65536 + (long)t * 256 + o, f));
        } else {
            int mm = m - 2304;
            int ty = mm / 256, o = mm % 256;
            WaT[(size_t)ty * 65536 + (size_t)o * 256 + t] =
                f2us(ld(Wa, (long)ty * 65536 + (long)t * 256 + o, f));
        }
    } else if (b < 15620) {
        int f = *flag;
        long i = ((long)(b - 3120) * 256 + t) * 4;
        if (i < (long)NN * 256) {
            if (f) {
                float4 v = *(const float4*)((const float*)x + i);
                ushort4 p; p.x = f2us(v.x); p.y = f2us(v.y); p.z = f2us(v.z); p.w = f2us(v.w);
                *(ushort4*)(xb + i) = p;
            } else {
                *(ushort4*)(xb + i) = *(const ushort4*)((const u16*)x + i);
            }
        }
    } else if (b < 15816) {
        __shared__ int lc[TN], lbase[TN];
        if (t < TN) lc[t] = 0;
        __syncthreads();
        int n = (b - 15620) * 256 + t;
        int pos = -1, ty = 0;
        if (n < NN) {
            ty = node_type[n];
            pos = atomicAdd(&lc[ty], 1);
        }
        __syncthreads();
        if (t < TN) lbase[t] = atomicAdd(&cnts[t], lc[t]);
        __syncthreads();
        if (n < NN) lists[ty * NN + lbase[ty] + pos] = n;
    } else {
        int e = (b - 15816) * 256 + t;
        if (e < EE) atomicAdd(&cnt[etype[e] * NN + edst[e]], 1u);
    }
}

// ---------------- 3-phase exclusive scan over SS segments ----------------
__global__ __launch_bounds__(256) void scanA(const unsigned* __restrict__ cnt,
                                             unsigned* __restrict__ csums) {
    __shared__ unsigned s[256];
    int b = blockIdx.x, t = threadIdx.x;
    int s0 = b * 1024 + t * 4;
    unsigned v = 0;
    if (s0 + 3 < SS) { uint4 u = *(const uint4*)&cnt[s0]; v = u.x + u.y + u.z + u.w; }
    else { for (int j = 0; j < 4; ++j) if (s0 + j < SS) v += cnt[s0 + j]; }
    s[t] = v;
    __syncthreads();
    for (int st = 128; st > 0; st >>= 1) {
        if (t < st) s[t] += s[t + st];
        __syncthreads();
    }
    if (t == 0) csums[b] = s[0];
}

__global__ __launch_bounds__(256) void scanB(unsigned* __restrict__ csums,
                                             int* __restrict__ base) {
    __shared__ unsigned s[512];
    int t = threadIdx.x;
    unsigned a = (t < NCHUNK) ? csums[t] : 0u;
    unsigned b = (256 + t < NCHUNK) ? csums[256 + t] : 0u;
    s[t] = a; s[256 + t] = b;
    __syncthreads();
    for (int st = 1; st < 512; st <<= 1) {
        unsigned x0 = (t >= st) ? s[t - st] : 0u;
        unsigned x1 = (256 + t >= st) ? s[256 + t - st] : 0u;
        __syncthreads();
        s[t] += x0; s[256 + t] += x1;
        __syncthreads();
    }
    if (t < NCHUNK) csums[t] = s[t] - a;
    if (256 + t < NCHUNK) csums[256 + t] = s[256 + t] - b;
    if (t == 0) base[SS] = (int)s[NCHUNK - 1];
}

__global__ __launch_bounds__(256) void scanC(const unsigned* __restrict__ cnt,
        const unsigned* __restrict__ csums, int* __restrict__ base) {
    __shared__ unsigned s[256];
    int b = blockIdx.x, t = threadIdx.x;
    int s0 = b * 1024 + t * 4;
    unsigned vs[4] = {0u, 0u, 0u, 0u};
    if (s0 + 3 < SS) { uint4 u = *(const uint4*)&cnt[s0]; vs[0]=u.x; vs[1]=u.y; vs[2]=u.z; vs[3]=u.w; }
    else { for (int j = 0; j < 4; ++j) if (s0 + j < SS) vs[j] = cnt[s0 + j]; }
    unsigned v = vs[0] + vs[1] + vs[2] + vs[3];
    s[t] = v;
    __syncthreads();
    for (int st = 1; st < 256; st <<= 1) {
        unsigned x = (t >= st) ? s[t - st] : 0u;
        __syncthreads();
        s[t] += x;
        __syncthreads();
    }
    unsigned run = csums[b] + s[t] - v;
    for (int j = 0; j < 4; ++j) {
        if (s0 + j < SS) { base[s0 + j] = (int)run; run += vs[j]; }
    }
}

// ---------------- scatter edges into seg-sorted order (consumes cnt) ----------------
__global__ __launch_bounds__(256) void scatter_edges(const int* __restrict__ edst,
        const int* __restrict__ etype, const int* __restrict__ base,
        unsigned* __restrict__ cnt, int* __restrict__ sorted) {
    int e = blockIdx.x * 256 + threadIdx.x;
    if (e >= EE) return;
    int seg = etype[e] * NN + edst[e];
    unsigned old = atomicSub(&cnt[seg], 1u);
    sorted[base[seg] + (int)old - 1] = e;
}

// ---------------- k/q/v typed linear via MFMA (32 same-type nodes / block) ----------------
// launch_bounds(256,2): VGPR cap 256 so the 12 A-frag loads/kt stay in flight.
__global__ __launch_bounds__(256, 2) void k1_mfma(const u16* __restrict__ xb,
        const u16* __restrict__ WallT,
        const void* __restrict__ bk, const void* __restrict__ bq,
        const void* __restrict__ bv,
        const int* __restrict__ lists, const int* __restrict__ cnts,
        const int* __restrict__ flag,
        u16* __restrict__ kb, u16* __restrict__ qb, u16* __restrict__ vb) {
    int f = *flag;
    int tt = blockIdx.x % TN, tile = blockIdx.x / TN;
    int cnt = cnts[tt];
    int start = tile * 32;
    if (start >= cnt) return;
    __shared__ int nl[32];
    // overlay: xs = lbuf viewed [32][280] (17.9KB), st = lbuf viewed [32][780] (49.9KB)
    __shared__ __align__(16) u16 lbuf[32 * 780];
    int t = threadIdx.x;
    if (t < 32) nl[t] = (start + t < cnt) ? lists[tt * NN + start + t] : -1;
    __syncthreads();
    {
        int i = t >> 4, g = t & 15;
        #pragma unroll
        for (int i2 = 0; i2 < 2; ++i2) {
            int row = i + i2 * 16;
            int node = nl[row];
            uint4 a = {0, 0, 0, 0}, b = {0, 0, 0, 0};
            if (node >= 0) {
                const uint4* src = (const uint4*)(xb + (size_t)node * 256 + g * 16);
                a = src[0]; b = src[1];
            }
            *(uint4*)&lbuf[row * 280 + g * 16] = a;
            *(uint4*)&lbuf[row * 280 + g * 16 + 8] = b;
        }
    }
    __syncthreads();
    int w = t >> 6, lane = t & 63, ln = lane & 15, quad = lane >> 4;
    const u16* Wt = WallT + (size_t)tt * 768 * 256;
    f32x4 acc0[12], acc1[12];
    #pragma unroll
    for (int j = 0; j < 12; ++j) {
        acc0[j] = (f32x4){0.f, 0.f, 0.f, 0.f};
        acc1[j] = (f32x4){0.f, 0.f, 0.f, 0.f};
    }
    #pragma unroll 2
    for (int kt = 0; kt < 8; ++kt) {
        bf16x8 A[12];
        #pragma unroll
        for (int jt = 0; jt < 12; ++jt)
            A[jt] = *(const bf16x8*)(Wt + (size_t)(w * 192 + jt * 16 + ln) * 256 + kt * 32 + quad * 8);
        bf16x8 B0 = *(const bf16x8*)&lbuf[ln * 280 + kt * 32 + quad * 8];
        bf16x8 B1 = *(const bf16x8*)&lbuf[(16 + ln) * 280 + kt * 32 + quad * 8];
        #pragma unroll
        for (int jt = 0; jt < 12; ++jt) {
            acc0[jt] = __builtin_amdgcn_mfma_f32_16x16x32_bf16(A[jt], B0, acc0[jt], 0, 0, 0);
            acc1[jt] = __builtin_amdgcn_mfma_f32_16x16x32_bf16(A[jt], B1, acc1[jt], 0, 0, 0);
        }
    }
    __syncthreads();   // xs dead; lbuf becomes st[32][780]
    #pragma unroll
    for (int jt = 0; jt < 12; ++jt) {
        int jc = w * 192 + jt * 16 + quad * 4;
        ushort4 p0, p1;
        p0.x = f2us(acc0[jt][0]); p0.y = f2us(acc0[jt][1]);
        p0.z = f2us(acc0[jt][2]); p0.w = f2us(acc0[jt][3]);
        p1.x = f2us(acc1[jt][0]); p1.y = f2us(acc1[jt][1]);
        p1.z = f2us(acc1[jt][2]); p1.w = f2us(acc1[jt][3]);
        *(ushort4*)&lbuf[ln * 780 + jc] = p0;
        *(ushort4*)&lbuf[(16 + ln) * 780 + jc] = p1;
    }
    __syncthreads();
    float bkv = ld(bk, tt * 256 + t, f);
    float bqv = ld(bq, tt * 256 + t, f);
    float bvv = ld(bv, tt * 256 + t, f);
    for (int i = 0; i < 32; ++i) {
        int node = nl[i];
        if (node < 0) break;
        size_t o = (size_t)node * 256 + t;
        kb[o] = f2us(busf(lbuf[i * 780 + t])       + bkv);
        qb[o] = f2us(busf(lbuf[i * 780 + 256 + t]) + bqv);
        vb[o] = f2us(busf(lbuf[i * 780 + 512 + t]) + bvv);
    }
}

// ---------------- per-r: qrel = rel_att @ q, vrel = rel_msg^T @ v (MFMA) ----------------
__global__ __launch_bounds__(256) void relqv(const u16* __restrict__ qb,
        const u16* __restrict__ vb,
        const u16* __restrict__ MTa, const u16* __restrict__ MTm, int r,
        u16* __restrict__ qrel, u16* __restrict__ vrel) {
    int nb = blockIdx.x * 16;
    int t = threadIdx.x, h = t >> 6, lane = t & 63, ln = lane & 15, quad = lane >> 4;
    __shared__ u16 stQ[16][264];
    __shared__ u16 stV[16][264];

    const u16* qp = qb + (size_t)(nb + ln) * 256 + h * 64 + quad * 8;
    const u16* vp = vb + (size_t)(nb + ln) * 256 + h * 64 + quad * 8;
    bf16x8 Bq0 = *(const bf16x8*)(qp);
    bf16x8 Bq1 = *(const bf16x8*)(qp + 32);
    bf16x8 Bv0 = *(const bf16x8*)(vp);
    bf16x8 Bv1 = *(const bf16x8*)(vp + 32);

    long mtbase = (long)(r * HN + h) * 4096;
    #pragma unroll
    for (int mt = 0; mt < 4; ++mt) {
        const u16* ap = MTa + mtbase + (mt * 16 + ln) * 64 + quad * 8;
        const u16* mp = MTm + mtbase + (mt * 16 + ln) * 64 + quad * 8;
        bf16x8 Aa0 = *(const bf16x8*)(ap);
        bf16x8 Aa1 = *(const bf16x8*)(ap + 32);
        bf16x8 Am0 = *(const bf16x8*)(mp);
        bf16x8 Am1 = *(const bf16x8*)(mp + 32);
        f32x4 accQ = {0.f, 0.f, 0.f, 0.f};
        f32x4 accV = {0.f, 0.f, 0.f, 0.f};
        accQ = __builtin_amdgcn_mfma_f32_16x16x32_bf16(Aa0, Bq0, accQ, 0, 0, 0);
        accQ = __builtin_amdgcn_mfma_f32_16x16x32_bf16(Aa1, Bq1, accQ, 0, 0, 0);
        accV = __builtin_amdgcn_mfma_f32_16x16x32_bf16(Am0, Bv0, accV, 0, 0, 0);
        accV = __builtin_amdgcn_mfma_f32_16x16x32_bf16(Am1, Bv1, accV, 0, 0, 0);
        int jc = h * 64 + mt * 16 + quad * 4;
        ushort4 pq, pv;
        pq.x = f2us(accQ[0]); pq.y = f2us(accQ[1]); pq.z = f2us(accQ[2]); pq.w = f2us(accQ[3]);
        pv.x = f2us(accV[0]); pv.y = f2us(accV[1]); pv.z = f2us(accV[2]); pv.w = f2us(accV[3]);
        *(ushort4*)&stQ[ln][jc] = pq;
        *(ushort4*)&stV[ln][jc] = pv;
    }
    __syncthreads();
    #pragma unroll 4
    for (int i = 0; i < 16; ++i) {
        qrel[(size_t)(nb + i) * 256 + t] = stQ[i][t];
        vrel[(size_t)(nb + i) * 256 + t] = stV[i][t];
    }
}

// ---------------- fused attention + aggregation for relation r ----------------
// block = CD consecutive dsts; edges contiguous in sorted[].
__global__ __launch_bounds__(256) void k2k4(const u16* __restrict__ kb,
        const u16* __restrict__ qrel, const u16* __restrict__ vrel,
        const void* __restrict__ rel_pri,
        const int* __restrict__ sorted, const int* __restrict__ base,
        const int* __restrict__ esrc, const int* __restrict__ edst,
        const int* __restrict__ flag, int r,
        u16* __restrict__ attex_g, void* tacc) {
    int f = *flag;
    int c0 = blockIdx.x * CD;
    int nd = min(CD, NN - c0);
    int segb = r * NN + c0;
    __shared__ float attL[1280];    // first 320 edges' exp (per head)
    __shared__ int srcL[1280];      // first 1280 edges' src
    __shared__ float denomL[CD * HN];
    __shared__ int sb_[CD + 1];
    int t = threadIdx.x;
    if (t < CD * HN) denomL[t] = 0.f;
    if (t <= nd) sb_[t] = base[segb + t];
    __syncthreads();
    int b0 = sb_[0], b1 = sb_[nd];
    int nE = b1 - b0;
    // phase A: att logits -> exp (thread per edge-head)
    for (int i = t; i < nE * 4; i += 256) {
        int ei = i >> 2;
        int e = sorted[b0 + ei];
        int h = i & 3;
        int s = esrc[e], dv = edst[e];
        if (h == 0 && ei < 1280) srcL[ei] = s;
        const uint4* kp = (const uint4*)(kb + (size_t)s * 256 + h * 64);
        const uint4* qp = (const uint4*)(qrel + (size_t)dv * 256 + h * 64);
        float dot = 0.f;
        #pragma unroll
        for (int ii = 0; ii < 8; ++ii) {
            uint4 a = kp[ii], b = qp[ii];
            dot += blo(a.x) * blo(b.x) + bhi(a.x) * bhi(b.x);
            dot += blo(a.y) * blo(b.y) + bhi(a.y) * bhi(b.y);
            dot += blo(a.z) * blo(b.z) + bhi(a.z) * bhi(b.z);
            dot += blo(a.w) * blo(b.w) + bhi(a.w) * bhi(b.w);
        }
        float attv = dot * ld(rel_pri, r * HN + h, f) * 0.125f;
        attv = fminf(fmaxf(attv, -50.f), 50.f);
        float ex = expf(attv);
        if (i < 1280) attL[i] = ex;
        else attex_g[(size_t)b0 * 4 + i] = f2us(ex);   // statistical never-path
        atomicAdd(&denomL[(dv - c0) * HN + h], ex);
    }
    __syncthreads();
    // phase B: wave per dst, lane dd covers dims dd*4..dd*4+3 (head dd>>4)
    int w = t >> 6, lane = t & 63;
    for (int i = w; i < nd; i += 4) {
        int sb = sb_[i], se = sb_[i + 1];
        long o = (long)(c0 + i) * 256 + lane * 4;
        if (se == sb) {
            if (r == 0) {
                if (f) { float4 z = {0.f, 0.f, 0.f, 0.f}; *(float4*)((float*)tacc + o) = z; }
                else   { ushort4 z = {0, 0, 0, 0}; *(ushort4*)((u16*)tacc + o) = z; }
            }
            continue;
        }
        float a0 = 0.f, a1 = 0.f, a2 = 0.f, a3 = 0.f;
        if (r != 0) {
            if (f) { float4 v = *(const float4*)((const float*)tacc + o);
                     a0 = v.x; a1 = v.y; a2 = v.z; a3 = v.w; }
            else   { ushort4 v = *(const ushort4*)((const u16*)tacc + o);
                     a0 = busf(v.x); a1 = busf(v.y); a2 = busf(v.z); a3 = busf(v.w); }
        }
        int h = lane >> 4;
        float inv = 1.f / denomL[i * HN + h];
        for (int idx = sb; idx < se; ++idx) {
            int rel = idx - b0;
            int li = rel * 4 + h;
            float wgt = ((li < 1280) ? attL[li] : busf(attex_g[(size_t)idx * 4 + h])) * inv;
            int s = (rel < 1280) ? srcL[rel] : esrc[sorted[idx]];
            ushort4 v = *(const ushort4*)(vrel + (size_t)s * 256 + lane * 4);
            a0 += wgt * busf(v.x); a1 += wgt * busf(v.y);
            a2 += wgt * busf(v.z); a3 += wgt * busf(v.w);
        }
        if (f) { float4 v = {a0, a1, a2, a3}; *(float4*)((float*)tacc + o) = v; }
        else   { ushort4 v; v.x = f2us(a0); v.y = f2us(a1); v.z = f2us(a2); v.w = f2us(a3);
                 *(ushort4*)((u16*)tacc + o) = v; }
    }
}

// ---------------- fused out-linear (MFMA) + skip-gate + LayerNorm ----------------
__global__ __launch_bounds__(256, 4) void k5_fused(const void* __restrict__ x,
        const void* tacc, const u16* __restrict__ WaT,
        const void* __restrict__ ba, const void* __restrict__ skip,
        const void* __restrict__ ln_g, const void* __restrict__ ln_b,
        const int* __restrict__ base,
        const int* __restrict__ lists, const int* __restrict__ cnts,
        const int* __restrict__ flag, void* out) {
    int f = *flag;
    int tt = blockIdx.x % TN, tile = blockIdx.x / TN;
    int cnt = cnts[tt];
    int start = tile * 16;
    if (start >= cnt) return;
    __shared__ int nl[16];
    __shared__ float invs[16];
    __shared__ int hasv[16];
    __shared__ __align__(16) u16 xs[16][280];
    __shared__ __align__(16) float st[16][264];
    __shared__ float red1[256], red2[256];
    __shared__ float mu_[16], rs_[16];
    int t = threadIdx.x;
    if (t < 16) {
        int node = (start + t < cnt) ? lists[tt * NN + start + t] : -1;
        nl[t] = node;
        int nrel = 0;
        if (node >= 0) {
            #pragma unroll
            for (int r = 0; r < RN; ++r)
                nrel += (base[r * NN + node + 1] > base[r * NN + node]) ? 1 : 0;
        }
        hasv[t] = nrel;
        invs[t] = (nrel > 0) ? 1.f / (float)nrel : 1.f;
    }
    __syncthreads();
    {
        int i = t >> 4, g = t & 15;
        int node = nl[i];
        float inv = invs[i];
        u16 buf[16];
        if (node >= 0) {
            long o = (long)node * 256 + g * 16;
            if (f) {
                const float* src = (const float*)tacc + o;
                #pragma unroll
                for (int j = 0; j < 16; ++j) buf[j] = f2us(src[j] * inv);
            } else {
                const u16* src = (const u16*)tacc + o;
                #pragma unroll
                for (int j = 0; j < 16; ++j) buf[j] = f2us(busf(src[j]) * inv);
            }
        } else {
            #pragma unroll
            for (int j = 0; j < 16; ++j) buf[j] = 0;
        }
        #pragma unroll
        for (int j = 0; j < 16; ++j) xs[i][g * 16 + j] = buf[j];
    }
    __syncthreads();
    int w = t >> 6, lane = t & 63, ln = lane & 15, quad = lane >> 4;
    const u16* Wt = WaT + (size_t)tt * 65536;
    f32x4 acc[4];
    #pragma unroll
    for (int j = 0; j < 4; ++j) acc[j] = (f32x4){0.f, 0.f, 0.f, 0.f};
    #pragma unroll
    for (int kt = 0; kt < 8; ++kt) {
        bf16x8 A4[4];
        #pragma unroll
        for (int jt = 0; jt < 4; ++jt)
            A4[jt] = *(const bf16x8*)(Wt + (size_t)(w * 64 + jt * 16 + ln) * 256 + kt * 32 + quad * 8);
        bf16x8 B = *(const bf16x8*)&xs[ln][kt * 32 + quad * 8];
        #pragma unroll
        for (int jt = 0; jt < 4; ++jt)
            acc[jt] = __builtin_amdgcn_mfma_f32_16x16x32_bf16(A4[jt], B, acc[jt], 0, 0, 0);
    }
    #pragma unroll
    for (int jt = 0; jt < 4; ++jt) {
        int jc = w * 64 + jt * 16 + quad * 4;
        #pragma unroll
        for (int rg = 0; rg < 4; ++rg)
            st[ln][jc + rg] = acc[jt][rg] + ld(ba, tt * 256 + jc + rg, f);
    }
    __syncthreads();
    float sk = ld(skip, tt, f);
    float alpha = 1.f / (1.f + expf(-sk));
    {
        int i = t >> 4, g = t & 15;
        int node = nl[i];
        float p1 = 0.f, p2 = 0.f;
        if (node >= 0) {
            #pragma unroll
            for (int j = 0; j < 16; ++j) {
                int o = g * 16 + j;
                float xv = ld(x, (long)node * 256 + o, f);
                float ov = st[i][o] * alpha + xv * (1.f - alpha);
                st[i][o] = ov;
                p1 += ov; p2 += ov * ov;
            }
        }
        red1[t] = p1; red2[t] = p2;
    }
    __syncthreads();
    for (int s = 8; s > 0; s >>= 1) {
        if ((t & 15) < s) { red1[t] += red1[t + s]; red2[t] += red2[t + s]; }
        __syncthreads();
    }
    if ((t & 15) == 0) {
        int i = t >> 4;
        float mu = red1[t] * (1.f / 256.f);
        float ms = red2[t] * (1.f / 256.f);
        float var = fmaxf(ms - mu * mu, 0.f);
        mu_[i] = mu; rs_[i] = rsqrtf(var + 1e-5f);
    }
    __syncthreads();
    float g_ = ld(ln_g, tt * 256 + t, f);
    float b_ = ld(ln_b, tt * 256 + t, f);
    for (int i = 0; i < 16; ++i) {
        int node = nl[i];
        if (node < 0) break;
        float resv;
        if (hasv[i] > 0) resv = (st[i][t] - mu_[i]) * rs_[i] * g_ + b_;
        else             resv = ld(x, (long)node * 256 + t, f);
        if (f) ((float*)out)[(long)node * 256 + t] = resv;
        else   ((u16*)out)[(long)node * 256 + t] = f2us(resv);
    }
}

extern "C" void kernel_launch(void* const* d_in, const int* in_sizes, int n_in,
                              void* d_out, int out_size, void* d_ws, size_t ws_size,
                              hipStream_t stream) {
    const void* x       = d_in[0];
    const void* Wk      = d_in[1];
    const void* bk      = d_in[2];
    const void* Wq      = d_in[3];
    const void* bq      = d_in[4];
    const void* Wv      = d_in[5];
    const void* bv      = d_in[6];
    const void* Wa      = d_in[7];
    const void* ba      = d_in[8];
    const void* rel_pri = d_in[9];
    const void* rel_att = d_in[10];
    const void* rel_msg = d_in[11];
    const void* skip    = d_in[12];
    const void* ln_g    = d_in[13];
    const void* ln_b    = d_in[14];
    const int* node_type = (const int*)d_in[15];
    const int* edge_src  = (const int*)d_in[16];
    const int* edge_dst  = (const int*)d_in[17];
    const int* edge_type = (const int*)d_in[18];
    char* w = (char*)d_ws;

    // layout (bytes) — total 137,767,552 <= proven ws floor 141,000,128
    u16*      kb     = (u16*)(w);                    // 25,600,000
    u16*      qb     = (u16*)(w + 25600000);         // 25,600,000
    u16*      vb     = (u16*)(w + 51200000);         // 25,600,000
    u16*      qrel   = (u16*)(w + 76800000);         // 25,600,000 (xb before r-loop)
    u16*      xb     = (u16*)(w + 76800000);         //   overlay
    u16*      vrel   = (u16*)(w + 102400000);        // 25,600,000
    u16*      attex  = (u16*)(w + 128000000);        //  3,200,000
    int*      sorted = (int*)(w + 131200000);        //  1,600,000
    int*      base   = (int*)(w + 132800000);        //  1,200,064
    int*      nlists = (int*)(w + 134000064);        //    600,000
    u16*      MTa    = (u16*)(w + 134600064);        //    196,608
    u16*      MTm    = (u16*)(w + 134796672);        //    196,608
    u16*      WallT  = (u16*)(w + 134993280);        //  1,179,648
    u16*      WaT    = (u16*)(w + 136172928);        //    393,216
    // zero region:
    unsigned* cnt    = (unsigned*)(w + 136566144);   //  1,200,000
    int*      ncnts  = (int*)(w + 137766144);        //         64
    int*      flag   = (int*)(w + 137766208);        //         64
    unsigned* csums  = (unsigned*)(w + 137766272);   //      1,280

    hipMemsetAsync(w + 136566144, 0, 1201408, stream);

    detect_dtype<<<dim3(1), dim3(256), 0, stream>>>(x, flag);
    prep<<<dim3(17379), dim3(256), 0, stream>>>(
        rel_att, rel_msg, Wk, Wq, Wv, Wa, x, node_type, edge_dst, edge_type,
        flag, MTa, MTm, WallT, WaT, xb, nlists, ncnts, cnt);
    scanA<<<dim3(NCHUNK), dim3(256), 0, stream>>>(cnt, csums);
    scanB<<<dim3(1), dim3(256), 0, stream>>>(csums, base);
    scanC<<<dim3(NCHUNK), dim3(256), 0, stream>>>(cnt, csums, base);
    scatter_edges<<<dim3((EE + 255) / 256), dim3(256), 0, stream>>>(
        edge_dst, edge_type, base, cnt, sorted);

    k1_mfma<<<dim3(TN * ((NN + 31) / 32)), dim3(256), 0, stream>>>(
        xb, WallT, bk, bq, bv, nlists, ncnts, flag, kb, qb, vb);

    for (int r = 0; r < RN; ++r) {
        relqv<<<dim3(NN / 16), dim3(256), 0, stream>>>(qb, vb, MTa, MTm, r, qrel, vrel);
        k2k4<<<dim3((NN + CD - 1) / CD), dim3(256), 0, stream>>>(
            kb, qrel, vrel, rel_pri, sorted, base, edge_src, edge_dst, flag, r,
            attex, d_out);
    }

    k5_fused<<<dim3(TN * (NN / 16)), dim3(256), 0, stream>>>(
        x, d_out, WaT, ba, skip, ln_g, ln_b, base, nlists, ncnts, flag, d_out);
}